// Round 13
// baseline (384.369 us; speedup 1.0000x reference)
//
#include <hip/hip_runtime.h>
#include <math.h>

#define NN 50000
#define NP 50176   // NN padded to 392*128 for guard-free GEMM
#define EE 800000
#define ETOT (EE + NN)
#define BB 50
#define PC 16  // pooling chunks per graph

typedef unsigned short u16;
typedef unsigned char u8;
typedef __attribute__((ext_vector_type(8))) short short8;
typedef __attribute__((ext_vector_type(4))) float floatx4;
typedef __attribute__((ext_vector_type(2))) float floatx2;

__device__ __forceinline__ float b2f(u16 u) {
  return __int_as_float(((int)u) << 16);
}
__device__ __forceinline__ u16 f2b(float f) {
  unsigned u = __float_as_uint(f);
  unsigned r = (u + 0x7fffu + ((u >> 16) & 1u)) >> 16;
  return (u16)r;
}
__device__ __forceinline__ u8 f2f8(float v) {
  return (u8)(__builtin_amdgcn_cvt_pk_fp8_f32(v, v, 0, false) & 0xFF);
}
__device__ __forceinline__ float readlane_f(float v, int l) {
  return __int_as_float(__builtin_amdgcn_readlane(__float_as_int(v), l));
}

// ---------------- CSR build ----------------
__global__ void count_kernel(const int* __restrict__ ei, int* __restrict__ cnt) {
  int e = blockIdx.x * blockDim.x + threadIdx.x;
  if (e >= ETOT) return;
  int d = (e < EE) ? ei[EE + e] : (e - EE);
  atomicAdd(&cnt[d], 1);
}

__global__ void scan1_kernel(const int* __restrict__ cnt, int* __restrict__ rowp,
                             int* __restrict__ part) {
  __shared__ int s[512];
  int t = threadIdx.x;
  int i = blockIdx.x * 512 + t;
  int v = (i < NN) ? cnt[i] : 0;
  s[t] = v;
  __syncthreads();
  for (int off = 1; off < 512; off <<= 1) {
    int add = (t >= off) ? s[t - off] : 0;
    __syncthreads();
    s[t] += add;
    __syncthreads();
  }
  if (i < NN) rowp[i] = s[t] - v;
  if (t == 511) part[blockIdx.x] = s[511];
}

__global__ void scan2_kernel(int* __restrict__ part, int* __restrict__ rowp) {
  __shared__ int s[128];
  int t = threadIdx.x;
  int v = (t < 98) ? part[t] : 0;
  s[t] = v;
  __syncthreads();
  for (int off = 1; off < 128; off <<= 1) {
    int add = (t >= off) ? s[t - off] : 0;
    __syncthreads();
    s[t] += add;
    __syncthreads();
  }
  if (t < 98) part[t] = s[t] - v;
  if (t == 97) rowp[NN] = s[97];
}

__global__ void scan3_kernel(int* __restrict__ rowp, const int* __restrict__ part) {
  int i = blockIdx.x * 512 + threadIdx.x;
  if (i < NN) rowp[i] += part[blockIdx.x];
}

__global__ void fill_kernel(const int* __restrict__ ei, const int* __restrict__ rowp,
                            int* __restrict__ cur, int* __restrict__ col) {
  int e = blockIdx.x * blockDim.x + threadIdx.x;
  if (e >= ETOT) return;
  int s, d;
  if (e < EE) { s = ei[e]; d = ei[EE + e]; } else { s = e - EE; d = s; }
  int p = atomicAdd(&cur[d], 1);
  col[rowp[d] + p] = s;
}

// ---------------- fused dtype prep ----------------
__global__ void prep_kernel(const float* __restrict__ x, const float* __restrict__ W1,
                            const float* __restrict__ W2, const float* __restrict__ W3,
                            u16* __restrict__ xb, u16* __restrict__ W1t,
                            u16* __restrict__ W2t, u16* __restrict__ W3t) {
  const int T0 = NP * 32, T1 = T0 + 8192, T2 = T1 + 65536, T3 = T2 + 16384;
  int i = blockIdx.x * 256 + threadIdx.x;
  if (i < T0) {
    int n = i >> 5, c = i & 31;
    xb[i] = (n < NN && c < 15) ? f2b(x[n * 15 + c]) : (u16)0;
  } else if (i < T1) {
    int j = i - T0, n = j >> 5, k = j & 31;
    W1t[j] = (k < 15) ? f2b(W1[k * 256 + n]) : (u16)0;
  } else if (i < T2) {
    int j = i - T1, n = j >> 8, k = j & 255;
    W2t[j] = f2b(W2[k * 256 + n]);
  } else if (i < T3) {
    int j = i - T2, n = j >> 8, k = j & 255;
    W3t[j] = f2b(W3[k * 64 + n]);
  }
}

// ---------------- bf16 MFMA GEMM + fused attention-score epilogue (R8 proven) ----------------
template <int BK, bool F8>
__global__ __launch_bounds__(256) void gemm_bf16_kernel(
    const u16* __restrict__ A, const u16* __restrict__ Bt, u16* __restrict__ C,
    u8* __restrict__ C8, int K, int N, const float* __restrict__ aS,
    const float* __restrict__ aD, float* __restrict__ as_o,
    float* __restrict__ ad_o, int Hh) {
  __shared__ u16 Al[128][BK + 8];
  __shared__ u16 Bl[64][BK + 8];
  __shared__ float sS[4][64], sD[4][64];
  int R0 = blockIdx.x * 128, C0 = blockIdx.y * 64;
  int wid = threadIdx.x >> 6, lane = threadIdx.x & 63;
  int wr = (wid >> 1) * 64, wc = (wid & 1) * 32;
  int lrow = lane & 15, lk8 = (lane >> 4) * 8;
  int rq = (lane >> 4) * 4;
  const int Q4 = BK / 4;
  const int nA = 128 * Q4, nB = 64 * Q4;
  floatx4 acc[4][2];
#pragma unroll
  for (int i = 0; i < 4; ++i)
#pragma unroll
    for (int j = 0; j < 2; ++j) acc[i][j] = (floatx4){0.f, 0.f, 0.f, 0.f};

  for (int k0 = 0; k0 < K; k0 += BK) {
    for (int c = threadIdx.x; c < nA + nB; c += 256) {
      if (c < nA) {
        int r = c / Q4, o = (c % Q4) * 4;
        *(ushort4*)&Al[r][o] = *(const ushort4*)&A[(size_t)(R0 + r) * K + k0 + o];
      } else {
        int c2 = c - nA;
        int r = c2 / Q4, o = (c2 % Q4) * 4;
        *(ushort4*)&Bl[r][o] = *(const ushort4*)&Bt[(size_t)(C0 + r) * K + k0 + o];
      }
    }
    __syncthreads();
#pragma unroll
    for (int ks = 0; ks < BK / 32; ++ks) {
      short8 a[4], b[2];
#pragma unroll
      for (int i = 0; i < 4; ++i) a[i] = *(const short8*)&Al[wr + i * 16 + lrow][ks * 32 + lk8];
#pragma unroll
      for (int j = 0; j < 2; ++j) b[j] = *(const short8*)&Bl[wc + j * 16 + lrow][ks * 32 + lk8];
#pragma unroll
      for (int i = 0; i < 4; ++i)
#pragma unroll
        for (int j = 0; j < 2; ++j)
          acc[i][j] = __builtin_amdgcn_mfma_f32_16x16x32_bf16(a[i], b[j], acc[i][j], 0, 0, 0);
    }
    __syncthreads();
  }
#pragma unroll
  for (int i = 0; i < 4; ++i)
#pragma unroll
    for (int j = 0; j < 2; ++j)
#pragma unroll
      for (int q = 0; q < 4; ++q) {
        int gr = R0 + wr + i * 16 + rq + q;
        int gc = C0 + wc + j * 16 + lrow;
        if constexpr (F8)
          C8[(size_t)gr * N + gc] = f2f8(acc[i][j][q]);
        else
          C[(size_t)gr * N + gc] = f2b(acc[i][j][q]);
      }
  int hb = blockIdx.y * 64;
  float wS0 = aS[hb + wc + lrow], wS1 = aS[hb + wc + 16 + lrow];
  float wD0 = aD[hb + wc + lrow], wD1 = aD[hb + wc + 16 + lrow];
#pragma unroll
  for (int i = 0; i < 4; ++i)
#pragma unroll
    for (int q = 0; q < 4; ++q) {
      float vS = acc[i][0][q] * wS0 + acc[i][1][q] * wS1;
      float vD = acc[i][0][q] * wD0 + acc[i][1][q] * wD1;
#pragma unroll
      for (int o = 8; o; o >>= 1) {
        vS += __shfl_xor(vS, o, 64);
        vD += __shfl_xor(vD, o, 64);
      }
      if (lrow == 0) {
        int rl = i * 16 + rq + q;
        sS[wid][rl] = vS;
        sD[wid][rl] = vD;
      }
    }
  __syncthreads();
  if (threadIdx.x < 128) {
    int p = threadIdx.x >> 6, r = threadIdx.x & 63;
    int gr = R0 + p * 64 + r;
    as_o[(size_t)gr * Hh + blockIdx.y] = sS[2 * p][r] + sS[2 * p + 1][r];
    ad_o[(size_t)gr * Hh + blockIdx.y] = sD[2 * p][r] + sD[2 * p + 1][r];
  }
}

// ---------------- per-dst-wave score precompute: exl[i] = exp(leaky(as[col[i]]+ad[d])) ----------------
template <int LAYER>
__global__ __launch_bounds__(256) void escore4_kernel(
    const float* __restrict__ as_i, const float* __restrict__ ad_i,
    const int* __restrict__ rowp, const int* __restrict__ col,
    float4* __restrict__ exl) {
  int wid = threadIdx.x >> 6, lane = threadIdx.x & 63;
  int d = blockIdx.x * 4 + wid;
  int rp0 = rowp[d], rp1 = rowp[d + 1];
  float4 add = *(const float4*)&ad_i[(size_t)d * 4];
  for (int i = rp0 + lane; i < rp1; i += 64) {
    int s = col[i];
    float4 a = *(const float4*)&as_i[(size_t)s * 4];
    float e0 = a.x + add.x, e1 = a.y + add.y, e2 = a.z + add.z, e3 = a.w + add.w;
    e0 = (e0 > 0.f) ? e0 : 0.2f * e0;
    e1 = (e1 > 0.f) ? e1 : 0.2f * e1;
    e2 = (e2 > 0.f) ? e2 : 0.2f * e2;
    e3 = (e3 > 0.f) ? e3 : 0.2f * e3;
    exl[i] = make_float4(__expf(e0), __expf(e1), __expf(e2), __expf(e3));
  }
}

__global__ __launch_bounds__(256) void escore1_kernel(
    const float* __restrict__ as_i, const float* __restrict__ ad_i,
    const int* __restrict__ rowp, const int* __restrict__ col,
    float* __restrict__ exl) {
  int wid = threadIdx.x >> 6, lane = threadIdx.x & 63;
  int d = blockIdx.x * 4 + wid;
  int rp0 = rowp[d], rp1 = rowp[d + 1];
  float add = ad_i[d];
  for (int i = rp0 + lane; i < rp1; i += 64) {
    float e = as_i[col[i]] + add;
    e = (e > 0.f) ? e : 0.2f * e;
    exl[i] = __expf(e);
  }
}

// ---------------- agg4: batch-8 inner, ex from precomputed coalesced array ----------------
template <int LAYER>
__global__ __launch_bounds__(256) void agg4_kernel(
    const u8* __restrict__ h8, const float4* __restrict__ exl,
    const int* __restrict__ rowp, const int* __restrict__ col,
    const float* __restrict__ bias, u16* __restrict__ xo) {
  __shared__ float exs[4][64][4];
  int wid = threadIdx.x >> 6, lane = threadIdx.x & 63;
  int d = blockIdx.x * 4 + wid;
  int rp0 = rowp[d], deg = rowp[d + 1] - rp0;
  int hj = lane >> 4;
  int lq = lane << 2;
  float a0 = 0.f, a1 = 0.f, a2 = 0.f, a3 = 0.f;
  float den0 = 0.f, den1 = 0.f, den2 = 0.f, den3 = 0.f;

  for (int base = 0; base < deg; base += 64) {
    int i = base + lane;
    bool valid = i < deg;
    int s = valid ? col[rp0 + i] : 0;
    float4 xv = valid ? exl[rp0 + i] : make_float4(0.f, 0.f, 0.f, 0.f);
    den0 += xv.x; den1 += xv.y; den2 += xv.z; den3 += xv.w;
    *(float4*)&exs[wid][lane][0] = xv;
    __threadfence_block();
    int cnt = min(64, deg - base);
    int k8 = cnt & ~7;
    for (int k = 0; k < k8; k += 8) {
      unsigned wv[8];
      float qv[8];
#pragma unroll
      for (int u = 0; u < 8; ++u) {
        int sk = __builtin_amdgcn_readlane(s, k + u);
        qv[u] = exs[wid][k + u][hj];
        wv[u] = *(const unsigned*)&h8[(size_t)sk * 256 + lq];
      }
#pragma unroll
      for (int u = 0; u < 8; ++u) {
        floatx2 lo = __builtin_amdgcn_cvt_pk_f32_fp8(wv[u], false);
        floatx2 hi = __builtin_amdgcn_cvt_pk_f32_fp8(wv[u], true);
        a0 += qv[u] * lo.x;
        a1 += qv[u] * lo.y;
        a2 += qv[u] * hi.x;
        a3 += qv[u] * hi.y;
      }
    }
    for (int k = k8; k < cnt; ++k) {
      int sk = __builtin_amdgcn_readlane(s, k);
      float qk = exs[wid][k][hj];
      unsigned wv = *(const unsigned*)&h8[(size_t)sk * 256 + lq];
      floatx2 lo = __builtin_amdgcn_cvt_pk_f32_fp8(wv, false);
      floatx2 hi = __builtin_amdgcn_cvt_pk_f32_fp8(wv, true);
      a0 += qk * lo.x;
      a1 += qk * lo.y;
      a2 += qk * hi.x;
      a3 += qk * hi.y;
    }
  }
#pragma unroll
  for (int o = 32; o; o >>= 1) {
    den0 += __shfl_xor(den0, o, 64);
    den1 += __shfl_xor(den1, o, 64);
    den2 += __shfl_xor(den2, o, 64);
    den3 += __shfl_xor(den3, o, 64);
  }
  float den = (hj == 0) ? den0 : (hj == 1) ? den1 : (hj == 2) ? den2 : den3;
  float inv = 1.f / den;
  float4 bv = *(const float4*)&bias[lq];
  float v0 = a0 * inv + bv.x;
  float v1 = a1 * inv + bv.y;
  float v2 = a2 * inv + bv.z;
  float v3 = a3 * inv + bv.w;
  v0 = (v0 > 0.f) ? v0 : expm1f(v0);
  v1 = (v1 > 0.f) ? v1 : expm1f(v1);
  v2 = (v2 > 0.f) ? v2 : expm1f(v2);
  v3 = (v3 > 0.f) ? v3 : expm1f(v3);
  ushort4 o4;
  o4.x = f2b(v0); o4.y = f2b(v1); o4.z = f2b(v2); o4.w = f2b(v3);
  ((ushort4*)xo)[(size_t)d * 64 + lane] = o4;
}

// ---------------- agg1 + fused node-attention MLP (ex precomputed) ----------------
__global__ __launch_bounds__(256) void agg1na_kernel(
    const u16* __restrict__ h, const float* __restrict__ exl,
    const int* __restrict__ rowp, const int* __restrict__ col,
    const float* __restrict__ bias, float* __restrict__ xo,
    const float* __restrict__ Wna1, const float* __restrict__ bna1,
    const float* __restrict__ Wna2, const float* __restrict__ bna2,
    float* __restrict__ na) {
  __shared__ float Ws[2048];
  __shared__ float W2s[32];
  __shared__ float xrow[4][64];
  for (int i = threadIdx.x; i < 2048; i += 256) Ws[i] = Wna1[i];
  if (threadIdx.x < 32) W2s[threadIdx.x] = Wna2[threadIdx.x];
  __syncthreads();
  int wid = threadIdx.x >> 6, lane = threadIdx.x & 63;
  int d = blockIdx.x * 4 + wid;
  int rp0 = rowp[d], deg = rowp[d + 1] - rp0;
  float acc = 0.f, den = 0.f;
  for (int base = 0; base < deg; base += 64) {
    int i = base + lane;
    bool valid = i < deg;
    int s = valid ? col[rp0 + i] : 0;
    float ex = valid ? exl[rp0 + i] : 0.f;
    den += ex;
    int cnt = min(64, deg - base);
    int k8 = cnt & ~7;
    for (int k = 0; k < k8; k += 8) {
      int sA[8];
      float qA[8], hv[8];
#pragma unroll
      for (int u = 0; u < 8; ++u) {
        sA[u] = __builtin_amdgcn_readlane(s, k + u);
        qA[u] = readlane_f(ex, k + u);
      }
#pragma unroll
      for (int u = 0; u < 8; ++u) hv[u] = b2f(h[(size_t)sA[u] * 64 + lane]);
      float p0 = qA[0] * hv[0] + qA[1] * hv[1];
      float p1 = qA[2] * hv[2] + qA[3] * hv[3];
      float p2 = qA[4] * hv[4] + qA[5] * hv[5];
      float p3 = qA[6] * hv[6] + qA[7] * hv[7];
      acc += (p0 + p1) + (p2 + p3);
    }
    for (int k = k8; k < cnt; ++k) {
      int sk = __builtin_amdgcn_readlane(s, k);
      float qk = readlane_f(ex, k);
      acc += qk * b2f(h[(size_t)sk * 64 + lane]);
    }
  }
#pragma unroll
  for (int o = 32; o; o >>= 1) den += __shfl_xor(den, o, 64);
  float v = acc / den + bias[lane];
  v = (v > 0.f) ? v : expm1f(v);
  xo[(size_t)d * 64 + lane] = v;
  // per-wave node-attention MLP on the in-LDS x3 row
  xrow[wid][lane] = v;
  __threadfence_block();
  int j = lane & 31;
  int coff = (lane >> 5) * 32;
  float hj = 0.f;
#pragma unroll
  for (int c = 0; c < 32; ++c) hj += xrow[wid][coff + c] * Ws[(coff + c) * 32 + j];
  hj += __shfl_xor(hj, 32, 64);
  hj += bna1[j];
  float r = fmaxf(hj, 0.f) * W2s[j];
#pragma unroll
  for (int o = 16; o; o >>= 1) r += __shfl_xor(r, o, 64);
  if (lane == 0) na[d] = __expf(r + bna2[0]);
}

// ---------------- na sum + write ----------------
__global__ void na_sum_kernel(const float* __restrict__ na, float* __restrict__ gsum) {
  __shared__ float s[4];
  float acc = 0.f;
  for (int i = blockIdx.x * blockDim.x + threadIdx.x; i < NN; i += gridDim.x * blockDim.x)
    acc += na[i];
  for (int o = 32; o; o >>= 1) acc += __shfl_xor(acc, o, 64);
  int wid = threadIdx.x >> 6, lane = threadIdx.x & 63;
  if (lane == 0) s[wid] = acc;
  __syncthreads();
  if (threadIdx.x == 0) atomicAdd(gsum, s[0] + s[1] + s[2] + s[3]);
}

__global__ void na_write_kernel(const float* __restrict__ na, const float* __restrict__ gsum,
                                float* __restrict__ out) {
  int n = blockIdx.x * blockDim.x + threadIdx.x;
  if (n >= NN) return;
  out[n] = na[n] / gsum[0];
}

// ---------------- pooling stage 1 ----------------
__global__ void pool1_kernel(const float* __restrict__ x3, const int* __restrict__ batch,
                             float* __restrict__ ppsum, float* __restrict__ ppmax) {
  int b = blockIdx.x, c = blockIdx.y;
  int lane = threadIdx.x & 63, wid = threadIdx.x >> 6;
  int lo = 0, hi = NN;
  while (lo < hi) { int m = (lo + hi) >> 1; if (batch[m] < b) lo = m + 1; else hi = m; }
  int start = lo;
  lo = start; hi = NN;
  while (lo < hi) { int m = (lo + hi) >> 1; if (batch[m] < b + 1) lo = m + 1; else hi = m; }
  int end = lo;
  int len = end - start;
  int c0 = start + (int)((long)len * c / PC);
  int c1 = start + (int)((long)len * (c + 1) / PC);
  float acc = 0.f, mx = -INFINITY;
  for (int n = c0 + wid; n < c1; n += 4) {
    float v = x3[(size_t)n * 64 + lane];
    acc += v;
    mx = fmaxf(mx, v);
  }
  __shared__ float ssum[4][64], smax[4][64];
  ssum[wid][lane] = acc;
  smax[wid][lane] = mx;
  __syncthreads();
  if (wid == 0) {
    acc = ssum[0][lane] + ssum[1][lane] + ssum[2][lane] + ssum[3][lane];
    mx = fmaxf(fmaxf(smax[0][lane], smax[1][lane]), fmaxf(smax[2][lane], smax[3][lane]));
    size_t o = ((size_t)c * BB + b) * 64 + lane;
    ppsum[o] = acc;
    ppmax[o] = mx;
  }
}

// ---------------- pooling fold + classifier ----------------
__global__ void pool2cls_kernel(const float* __restrict__ ppsum, const float* __restrict__ ppmax,
                                const int* __restrict__ batch, const float* __restrict__ Wc1,
                                const float* __restrict__ bc1, const float* __restrict__ Wc2,
                                const float* __restrict__ bc2, const float* __restrict__ Wc3,
                                const float* __restrict__ bc3, float* __restrict__ out) {
  __shared__ float g[128], h1[128], h2[64], scnt;
  int b = blockIdx.x, t = threadIdx.x;
  if (t == 0) {
    int lo = 0, hi = NN;
    while (lo < hi) { int m = (lo + hi) >> 1; if (batch[m] < b) lo = m + 1; else hi = m; }
    int start = lo;
    lo = start; hi = NN;
    while (lo < hi) { int m = (lo + hi) >> 1; if (batch[m] < b + 1) lo = m + 1; else hi = m; }
    scnt = (float)(lo - start);
  }
  float s = 0.f, m = -INFINITY;
  if (t < 64) {
#pragma unroll
    for (int c = 0; c < PC; ++c) {
      size_t o = ((size_t)c * BB + b) * 64 + t;
      s += ppsum[o];
      m = fmaxf(m, ppmax[o]);
    }
  }
  __syncthreads();
  float cnt = scnt;
  if (t < 64) {
    g[t] = (cnt > 0.f) ? s / fmaxf(cnt, 1.f) : 0.f;
    g[64 + t] = (cnt > 0.f) ? m : 0.f;
  }
  __syncthreads();
  float v = bc1[t];
  for (int k = 0; k < 128; ++k) v += g[k] * Wc1[k * 128 + t];
  h1[t] = fmaxf(v, 0.f);
  __syncthreads();
  if (t < 64) {
    float v2 = bc2[t];
    for (int k = 0; k < 128; ++k) v2 += h1[k] * Wc2[k * 64 + t];
    h2[t] = fmaxf(v2, 0.f);
  }
  __syncthreads();
  if (t == 0) {
    float z = bc3[0];
    for (int k = 0; k < 64; ++k) z += h2[k] * Wc3[k];
    out[b] = 1.f / (1.f + expf(-z));
  }
}

extern "C" void kernel_launch(void* const* d_in, const int* in_sizes, int n_in,
                              void* d_out, int out_size, void* d_ws, size_t ws_size,
                              hipStream_t stream) {
  const float* x    = (const float*)d_in[0];
  const int*   ei   = (const int*)d_in[1];
  const int*   batch= (const int*)d_in[2];
  const float* W1 = (const float*)d_in[3];
  const float* aS1= (const float*)d_in[4];
  const float* aD1= (const float*)d_in[5];
  const float* b1 = (const float*)d_in[6];
  const float* W2 = (const float*)d_in[7];
  const float* aS2= (const float*)d_in[8];
  const float* aD2= (const float*)d_in[9];
  const float* b2 = (const float*)d_in[10];
  const float* W3 = (const float*)d_in[11];
  const float* aS3= (const float*)d_in[12];
  const float* aD3= (const float*)d_in[13];
  const float* b3 = (const float*)d_in[14];
  const float* Wna1=(const float*)d_in[15];
  const float* bna1=(const float*)d_in[16];
  const float* Wna2=(const float*)d_in[17];
  const float* bna2=(const float*)d_in[18];
  const float* Wc1=(const float*)d_in[19];
  const float* bc1=(const float*)d_in[20];
  const float* Wc2=(const float*)d_in[21];
  const float* bc2=(const float*)d_in[22];
  const float* Wc3=(const float*)d_in[23];
  const float* bc3=(const float*)d_in[24];
  float* out = (float*)d_out;

  char* w = (char*)d_ws;
  size_t off = 0;
  auto alloc = [&](size_t bytes) {
    void* p = w + off;
    off = (off + bytes + 255) & ~(size_t)255;
    return p;
  };
  u16* xb   = (u16*)alloc((size_t)NP * 32 * 2);
  u16* bufA = (u16*)alloc((size_t)NP * 256 * 2);       // h3 (bf16)
  u16* bufB = (u16*)alloc((size_t)NP * 256 * 2);       // y1 / y2 / x3(fp32)
  u8*  h8   = (u8*)alloc((size_t)NP * 256);            // fp8 h1 / h2
  u16* W1t  = (u16*)alloc((size_t)256 * 32 * 2);
  u16* W2t  = (u16*)alloc((size_t)256 * 256 * 2);
  u16* W3t  = (u16*)alloc((size_t)64 * 256 * 2);
  float* asb  = (float*)alloc((size_t)NP * 4 * 4);
  float* adb  = (float*)alloc((size_t)NP * 4 * 4);
  float* nab  = (float*)alloc((size_t)NN * 4);
  float4* exl4 = (float4*)alloc((size_t)ETOT * 16);    // per-edge exp scores
  int* rowp = (int*)alloc((size_t)(NN + 1) * 4);
  int* cntb = (int*)alloc((size_t)NN * 4);
  int* curb = (int*)alloc((size_t)NN * 4);
  float* gsum = (float*)alloc(256);
  size_t zspan = (size_t)((char*)gsum + 256 - (char*)cntb);
  int* colb = (int*)alloc((size_t)ETOT * 4);
  int* part = (int*)alloc(128 * 4);
  float* ppsum = (float*)alloc((size_t)PC * BB * 64 * 4);
  float* ppmax = (float*)alloc((size_t)PC * BB * 64 * 4);
  float* x3 = (float*)bufB;
  float* exl1 = (float*)exl4;
  (void)ws_size; (void)in_sizes; (void)n_in; (void)out_size;

  hipMemsetAsync(cntb, 0, zspan, stream);

  count_kernel<<<(ETOT + 255) / 256, 256, 0, stream>>>(ei, cntb);
  scan1_kernel<<<98, 512, 0, stream>>>(cntb, rowp, part);
  scan2_kernel<<<1, 128, 0, stream>>>(part, rowp);
  scan3_kernel<<<98, 512, 0, stream>>>(rowp, part);
  fill_kernel<<<(ETOT + 255) / 256, 256, 0, stream>>>(ei, rowp, curb, colb);

  const int PREP_TOT = NP * 32 + 8192 + 65536 + 16384;
  prep_kernel<<<(PREP_TOT + 255) / 256, 256, 0, stream>>>(x, W1, W2, W3, xb, W1t, W2t, W3t);

  const int GX = NP / 128;  // 392
  // layer 1: 15(->32) -> 256 (fp8 h)
  gemm_bf16_kernel<32, true><<<dim3(GX, 4), 256, 0, stream>>>(
      xb, W1t, nullptr, h8, 32, 256, aS1, aD1, asb, adb, 4);
  escore4_kernel<1><<<12500, 256, 0, stream>>>(asb, adb, rowp, colb, exl4);
  agg4_kernel<1><<<12500, 256, 0, stream>>>(h8, exl4, rowp, colb, b1, bufB);
  // layer 2: 256 -> 256 (fp8 h)
  gemm_bf16_kernel<64, true><<<dim3(GX, 4), 256, 0, stream>>>(
      bufB, W2t, nullptr, h8, 256, 256, aS2, aD2, asb, adb, 4);
  escore4_kernel<2><<<12500, 256, 0, stream>>>(asb, adb, rowp, colb, exl4);
  agg4_kernel<2><<<12500, 256, 0, stream>>>(h8, exl4, rowp, colb, b2, bufB);
  // layer 3: 256 -> 64 (bf16 h) + fused node-attention MLP
  gemm_bf16_kernel<64, false><<<dim3(GX, 1), 256, 0, stream>>>(
      bufB, W3t, bufA, nullptr, 256, 64, aS3, aD3, asb, adb, 1);
  escore1_kernel<<<12500, 256, 0, stream>>>(asb, adb, rowp, colb, exl1);
  agg1na_kernel<<<12500, 256, 0, stream>>>(bufA, exl1, rowp, colb, b3, x3,
                                           Wna1, bna1, Wna2, bna2, nab);

  na_sum_kernel<<<196, 256, 0, stream>>>(nab, gsum);
  na_write_kernel<<<(NN + 255) / 256, 256, 0, stream>>>(nab, gsum, out + BB);
  pool1_kernel<<<dim3(BB, PC), 256, 0, stream>>>(x3, batch, ppsum, ppmax);
  pool2cls_kernel<<<BB, 128, 0, stream>>>(ppsum, ppmax, batch, Wc1, bc1, Wc2, bc2,
                                          Wc3, bc3, out);
}

// Round 14
// 372.637 us; speedup vs baseline: 1.0315x; 1.0315x over previous
//
#include <hip/hip_runtime.h>
#include <math.h>

#define NN 50000
#define NP 50176   // NN padded to 392*128 for guard-free GEMM
#define EE 800000
#define ETOT (EE + NN)
#define BB 50
#define PC 16  // pooling chunks per graph

typedef unsigned short u16;
typedef unsigned char u8;
typedef __attribute__((ext_vector_type(8))) short short8;
typedef __attribute__((ext_vector_type(8))) unsigned short ushort8;
typedef __attribute__((ext_vector_type(4))) float floatx4;
typedef __attribute__((ext_vector_type(2))) float floatx2;

__device__ __forceinline__ float b2f(u16 u) {
  return __int_as_float(((int)u) << 16);
}
__device__ __forceinline__ u16 f2b(float f) {
  unsigned u = __float_as_uint(f);
  unsigned r = (u + 0x7fffu + ((u >> 16) & 1u)) >> 16;
  return (u16)r;
}
__device__ __forceinline__ u8 f2f8(float v) {
  return (u8)(__builtin_amdgcn_cvt_pk_fp8_f32(v, v, 0, false) & 0xFF);
}
__device__ __forceinline__ float readlane_f(float v, int l) {
  return __int_as_float(__builtin_amdgcn_readlane(__float_as_int(v), l));
}

// ---------------- CSR build ----------------
__global__ void count_kernel(const int* __restrict__ ei, int* __restrict__ cnt) {
  int e = blockIdx.x * blockDim.x + threadIdx.x;
  if (e >= ETOT) return;
  int d = (e < EE) ? ei[EE + e] : (e - EE);
  atomicAdd(&cnt[d], 1);
}

__global__ void scan1_kernel(const int* __restrict__ cnt, int* __restrict__ rowp,
                             int* __restrict__ part) {
  __shared__ int s[512];
  int t = threadIdx.x;
  int i = blockIdx.x * 512 + t;
  int v = (i < NN) ? cnt[i] : 0;
  s[t] = v;
  __syncthreads();
  for (int off = 1; off < 512; off <<= 1) {
    int add = (t >= off) ? s[t - off] : 0;
    __syncthreads();
    s[t] += add;
    __syncthreads();
  }
  if (i < NN) rowp[i] = s[t] - v;
  if (t == 511) part[blockIdx.x] = s[511];
}

__global__ void scan2_kernel(int* __restrict__ part, int* __restrict__ rowp) {
  __shared__ int s[128];
  int t = threadIdx.x;
  int v = (t < 98) ? part[t] : 0;
  s[t] = v;
  __syncthreads();
  for (int off = 1; off < 128; off <<= 1) {
    int add = (t >= off) ? s[t - off] : 0;
    __syncthreads();
    s[t] += add;
    __syncthreads();
  }
  if (t < 98) part[t] = s[t] - v;
  if (t == 97) rowp[NN] = s[97];
}

__global__ void scan3_kernel(int* __restrict__ rowp, const int* __restrict__ part) {
  int i = blockIdx.x * 512 + threadIdx.x;
  if (i < NN) rowp[i] += part[blockIdx.x];
}

__global__ void fill_kernel(const int* __restrict__ ei, const int* __restrict__ rowp,
                            int* __restrict__ cur, int* __restrict__ col) {
  int e = blockIdx.x * blockDim.x + threadIdx.x;
  if (e >= ETOT) return;
  int s, d;
  if (e < EE) { s = ei[e]; d = ei[EE + e]; } else { s = e - EE; d = s; }
  int p = atomicAdd(&cur[d], 1);
  col[rowp[d] + p] = s;
}

// ---------------- fused dtype prep ----------------
__global__ void prep_kernel(const float* __restrict__ x, const float* __restrict__ W1,
                            const float* __restrict__ W2, const float* __restrict__ W3,
                            u16* __restrict__ xb, u16* __restrict__ W1t,
                            u16* __restrict__ W2t, u16* __restrict__ W3t) {
  const int T0 = NP * 32, T1 = T0 + 8192, T2 = T1 + 65536, T3 = T2 + 16384;
  int i = blockIdx.x * 256 + threadIdx.x;
  if (i < T0) {
    int n = i >> 5, c = i & 31;
    xb[i] = (n < NN && c < 15) ? f2b(x[n * 15 + c]) : (u16)0;
  } else if (i < T1) {
    int j = i - T0, n = j >> 5, k = j & 31;
    W1t[j] = (k < 15) ? f2b(W1[k * 256 + n]) : (u16)0;
  } else if (i < T2) {
    int j = i - T1, n = j >> 8, k = j & 255;
    W2t[j] = f2b(W2[k * 256 + n]);
  } else if (i < T3) {
    int j = i - T2, n = j >> 8, k = j & 255;
    W3t[j] = f2b(W3[k * 64 + n]);
  }
}

// ---------------- 128x128 bf16 MFMA GEMM -> fp8 h + fused scores (H=4) ----------------
// C8[NP,256] = A[NP,K] @ Bt[256,K]^T. Waves 2x2, each 64x64 out (4x4 frags).
// Each wave's 64 cols = exactly one head -> pure-shfl score epilogue.
// (structure correctness-verified in R9; staging upgraded to 16B loads)
template <int BK>
__global__ __launch_bounds__(256) void gemm128_kernel(
    const u16* __restrict__ A, const u16* __restrict__ Bt, u8* __restrict__ C8,
    int K, const float* __restrict__ aS, const float* __restrict__ aD,
    float* __restrict__ as_o, float* __restrict__ ad_o) {
  __shared__ u16 Al[128][BK + 8];
  __shared__ u16 Bl[128][BK + 8];
  int R0 = blockIdx.x * 128, C0 = blockIdx.y * 128;
  int wid = threadIdx.x >> 6, lane = threadIdx.x & 63;
  int wr = (wid >> 1) * 64, wc = (wid & 1) * 64;
  int lrow = lane & 15, lk8 = (lane >> 4) * 8;
  int rq = (lane >> 4) * 4;
  const int Q8 = BK / 8;           // ushort8 per row
  const int nA8 = 128 * Q8;
  floatx4 acc[4][4];
#pragma unroll
  for (int i = 0; i < 4; ++i)
#pragma unroll
    for (int j = 0; j < 4; ++j) acc[i][j] = (floatx4){0.f, 0.f, 0.f, 0.f};

  for (int k0 = 0; k0 < K; k0 += BK) {
    for (int c = threadIdx.x; c < 2 * nA8; c += 256) {
      if (c < nA8) {
        int r = c / Q8, o = (c % Q8) * 8;
        *(ushort8*)&Al[r][o] = *(const ushort8*)&A[(size_t)(R0 + r) * K + k0 + o];
      } else {
        int c2 = c - nA8;
        int r = c2 / Q8, o = (c2 % Q8) * 8;
        *(ushort8*)&Bl[r][o] = *(const ushort8*)&Bt[(size_t)(C0 + r) * K + k0 + o];
      }
    }
    __syncthreads();
#pragma unroll
    for (int ks = 0; ks < BK / 32; ++ks) {
      short8 a[4], b[4];
#pragma unroll
      for (int i = 0; i < 4; ++i) a[i] = *(const short8*)&Al[wr + i * 16 + lrow][ks * 32 + lk8];
#pragma unroll
      for (int j = 0; j < 4; ++j) b[j] = *(const short8*)&Bl[wc + j * 16 + lrow][ks * 32 + lk8];
#pragma unroll
      for (int i = 0; i < 4; ++i)
#pragma unroll
        for (int j = 0; j < 4; ++j)
          acc[i][j] = __builtin_amdgcn_mfma_f32_16x16x32_bf16(a[i], b[j], acc[i][j], 0, 0, 0);
    }
    __syncthreads();
  }
  // fp8 h write
#pragma unroll
  for (int i = 0; i < 4; ++i)
#pragma unroll
    for (int j = 0; j < 4; ++j)
#pragma unroll
      for (int q = 0; q < 4; ++q) {
        int gr = R0 + wr + i * 16 + rq + q;
        int gc = C0 + wc + j * 16 + lrow;
        C8[(size_t)gr * 256 + gc] = f2f8(acc[i][j][q]);
      }
  // score epilogue: this wave's head (pure shfl)
  int hb = blockIdx.y * 2 + (wid & 1);
  float wS[4], wD[4];
#pragma unroll
  for (int j = 0; j < 4; ++j) {
    wS[j] = aS[hb * 64 + j * 16 + lrow];
    wD[j] = aD[hb * 64 + j * 16 + lrow];
  }
#pragma unroll
  for (int i = 0; i < 4; ++i)
#pragma unroll
    for (int q = 0; q < 4; ++q) {
      float vS = acc[i][0][q] * wS[0] + acc[i][1][q] * wS[1] +
                 acc[i][2][q] * wS[2] + acc[i][3][q] * wS[3];
      float vD = acc[i][0][q] * wD[0] + acc[i][1][q] * wD[1] +
                 acc[i][2][q] * wD[2] + acc[i][3][q] * wD[3];
#pragma unroll
      for (int o = 8; o; o >>= 1) {
        vS += __shfl_xor(vS, o, 64);
        vD += __shfl_xor(vD, o, 64);
      }
      if (lrow == 0) {
        int gr = R0 + wr + i * 16 + rq + q;
        as_o[(size_t)gr * 4 + hb] = vS;
        ad_o[(size_t)gr * 4 + hb] = vD;
      }
    }
}

// ---------------- 128x64 bf16 GEMM (layer 3) + scores (H=1) (R8 proven) ----------------
__global__ __launch_bounds__(256) void gemm64_kernel(
    const u16* __restrict__ A, const u16* __restrict__ Bt, u16* __restrict__ C,
    int K, const float* __restrict__ aS, const float* __restrict__ aD,
    float* __restrict__ as_o, float* __restrict__ ad_o) {
  const int BK = 64;
  __shared__ u16 Al[128][BK + 8];
  __shared__ u16 Bl[64][BK + 8];
  __shared__ float sS[4][64], sD[4][64];
  int R0 = blockIdx.x * 128;
  int wid = threadIdx.x >> 6, lane = threadIdx.x & 63;
  int wr = (wid >> 1) * 64, wc = (wid & 1) * 32;
  int lrow = lane & 15, lk8 = (lane >> 4) * 8;
  int rq = (lane >> 4) * 4;
  const int Q4 = BK / 4;
  const int nA = 128 * Q4, nB = 64 * Q4;
  floatx4 acc[4][2];
#pragma unroll
  for (int i = 0; i < 4; ++i)
#pragma unroll
    for (int j = 0; j < 2; ++j) acc[i][j] = (floatx4){0.f, 0.f, 0.f, 0.f};

  for (int k0 = 0; k0 < K; k0 += BK) {
    for (int c = threadIdx.x; c < nA + nB; c += 256) {
      if (c < nA) {
        int r = c / Q4, o = (c % Q4) * 4;
        *(ushort4*)&Al[r][o] = *(const ushort4*)&A[(size_t)(R0 + r) * K + k0 + o];
      } else {
        int c2 = c - nA;
        int r = c2 / Q4, o = (c2 % Q4) * 4;
        *(ushort4*)&Bl[r][o] = *(const ushort4*)&Bt[(size_t)r * K + k0 + o];
      }
    }
    __syncthreads();
#pragma unroll
    for (int ks = 0; ks < BK / 32; ++ks) {
      short8 a[4], b[2];
#pragma unroll
      for (int i = 0; i < 4; ++i) a[i] = *(const short8*)&Al[wr + i * 16 + lrow][ks * 32 + lk8];
#pragma unroll
      for (int j = 0; j < 2; ++j) b[j] = *(const short8*)&Bl[wc + j * 16 + lrow][ks * 32 + lk8];
#pragma unroll
      for (int i = 0; i < 4; ++i)
#pragma unroll
        for (int j = 0; j < 2; ++j)
          acc[i][j] = __builtin_amdgcn_mfma_f32_16x16x32_bf16(a[i], b[j], acc[i][j], 0, 0, 0);
    }
    __syncthreads();
  }
#pragma unroll
  for (int i = 0; i < 4; ++i)
#pragma unroll
    for (int j = 0; j < 2; ++j)
#pragma unroll
      for (int q = 0; q < 4; ++q) {
        int gr = R0 + wr + i * 16 + rq + q;
        C[(size_t)gr * 64 + wc + j * 16 + lrow] = f2b(acc[i][j][q]);
      }
  float wS0 = aS[wc + lrow], wS1 = aS[wc + 16 + lrow];
  float wD0 = aD[wc + lrow], wD1 = aD[wc + 16 + lrow];
#pragma unroll
  for (int i = 0; i < 4; ++i)
#pragma unroll
    for (int q = 0; q < 4; ++q) {
      float vS = acc[i][0][q] * wS0 + acc[i][1][q] * wS1;
      float vD = acc[i][0][q] * wD0 + acc[i][1][q] * wD1;
#pragma unroll
      for (int o = 8; o; o >>= 1) {
        vS += __shfl_xor(vS, o, 64);
        vD += __shfl_xor(vD, o, 64);
      }
      if (lrow == 0) {
        int rl = i * 16 + rq + q;
        sS[wid][rl] = vS;
        sD[wid][rl] = vD;
      }
    }
  __syncthreads();
  if (threadIdx.x < 128) {
    int p = threadIdx.x >> 6, r = threadIdx.x & 63;
    int gr = R0 + p * 64 + r;
    as_o[gr] = sS[2 * p][r] + sS[2 * p + 1][r];
    ad_o[gr] = sD[2 * p][r] + sD[2 * p + 1][r];
  }
}

// ---------------- per-dst-wave score precompute ----------------
template <int LAYER>
__global__ __launch_bounds__(256) void escore4_kernel(
    const float* __restrict__ as_i, const float* __restrict__ ad_i,
    const int* __restrict__ rowp, const int* __restrict__ col,
    float4* __restrict__ exl) {
  int wid = threadIdx.x >> 6, lane = threadIdx.x & 63;
  int d = blockIdx.x * 4 + wid;
  int rp0 = rowp[d], rp1 = rowp[d + 1];
  float4 add = *(const float4*)&ad_i[(size_t)d * 4];
  for (int i = rp0 + lane; i < rp1; i += 64) {
    int s = col[i];
    float4 a = *(const float4*)&as_i[(size_t)s * 4];
    float e0 = a.x + add.x, e1 = a.y + add.y, e2 = a.z + add.z, e3 = a.w + add.w;
    e0 = (e0 > 0.f) ? e0 : 0.2f * e0;
    e1 = (e1 > 0.f) ? e1 : 0.2f * e1;
    e2 = (e2 > 0.f) ? e2 : 0.2f * e2;
    e3 = (e3 > 0.f) ? e3 : 0.2f * e3;
    exl[i] = make_float4(__expf(e0), __expf(e1), __expf(e2), __expf(e3));
  }
}

__global__ __launch_bounds__(256) void escore1_kernel(
    const float* __restrict__ as_i, const float* __restrict__ ad_i,
    const int* __restrict__ rowp, const int* __restrict__ col,
    float* __restrict__ exl) {
  int wid = threadIdx.x >> 6, lane = threadIdx.x & 63;
  int d = blockIdx.x * 4 + wid;
  int rp0 = rowp[d], rp1 = rowp[d + 1];
  float add = ad_i[d];
  for (int i = rp0 + lane; i < rp1; i += 64) {
    float e = as_i[col[i]] + add;
    e = (e > 0.f) ? e : 0.2f * e;
    exl[i] = __expf(e);
  }
}

// ---------------- agg4: batch-8 inner, ex from precomputed coalesced array ----------------
template <int LAYER>
__global__ __launch_bounds__(256) void agg4_kernel(
    const u8* __restrict__ h8, const float4* __restrict__ exl,
    const int* __restrict__ rowp, const int* __restrict__ col,
    const float* __restrict__ bias, u16* __restrict__ xo) {
  __shared__ float exs[4][64][4];
  int wid = threadIdx.x >> 6, lane = threadIdx.x & 63;
  int d = blockIdx.x * 4 + wid;
  int rp0 = rowp[d], deg = rowp[d + 1] - rp0;
  int hj = lane >> 4;
  int lq = lane << 2;
  float a0 = 0.f, a1 = 0.f, a2 = 0.f, a3 = 0.f;
  float den0 = 0.f, den1 = 0.f, den2 = 0.f, den3 = 0.f;

  for (int base = 0; base < deg; base += 64) {
    int i = base + lane;
    bool valid = i < deg;
    int s = valid ? col[rp0 + i] : 0;
    float4 xv = valid ? exl[rp0 + i] : make_float4(0.f, 0.f, 0.f, 0.f);
    den0 += xv.x; den1 += xv.y; den2 += xv.z; den3 += xv.w;
    *(float4*)&exs[wid][lane][0] = xv;
    __threadfence_block();
    int cnt = min(64, deg - base);
    int k8 = cnt & ~7;
    for (int k = 0; k < k8; k += 8) {
      unsigned wv[8];
      float qv[8];
#pragma unroll
      for (int u = 0; u < 8; ++u) {
        int sk = __builtin_amdgcn_readlane(s, k + u);
        qv[u] = exs[wid][k + u][hj];
        wv[u] = *(const unsigned*)&h8[(size_t)sk * 256 + lq];
      }
#pragma unroll
      for (int u = 0; u < 8; ++u) {
        floatx2 lo = __builtin_amdgcn_cvt_pk_f32_fp8(wv[u], false);
        floatx2 hi = __builtin_amdgcn_cvt_pk_f32_fp8(wv[u], true);
        a0 += qv[u] * lo.x;
        a1 += qv[u] * lo.y;
        a2 += qv[u] * hi.x;
        a3 += qv[u] * hi.y;
      }
    }
    for (int k = k8; k < cnt; ++k) {
      int sk = __builtin_amdgcn_readlane(s, k);
      float qk = exs[wid][k][hj];
      unsigned wv = *(const unsigned*)&h8[(size_t)sk * 256 + lq];
      floatx2 lo = __builtin_amdgcn_cvt_pk_f32_fp8(wv, false);
      floatx2 hi = __builtin_amdgcn_cvt_pk_f32_fp8(wv, true);
      a0 += qk * lo.x;
      a1 += qk * lo.y;
      a2 += qk * hi.x;
      a3 += qk * hi.y;
    }
  }
#pragma unroll
  for (int o = 32; o; o >>= 1) {
    den0 += __shfl_xor(den0, o, 64);
    den1 += __shfl_xor(den1, o, 64);
    den2 += __shfl_xor(den2, o, 64);
    den3 += __shfl_xor(den3, o, 64);
  }
  float den = (hj == 0) ? den0 : (hj == 1) ? den1 : (hj == 2) ? den2 : den3;
  float inv = 1.f / den;
  float4 bv = *(const float4*)&bias[lq];
  float v0 = a0 * inv + bv.x;
  float v1 = a1 * inv + bv.y;
  float v2 = a2 * inv + bv.z;
  float v3 = a3 * inv + bv.w;
  v0 = (v0 > 0.f) ? v0 : expm1f(v0);
  v1 = (v1 > 0.f) ? v1 : expm1f(v1);
  v2 = (v2 > 0.f) ? v2 : expm1f(v2);
  v3 = (v3 > 0.f) ? v3 : expm1f(v3);
  ushort4 o4;
  o4.x = f2b(v0); o4.y = f2b(v1); o4.z = f2b(v2); o4.w = f2b(v3);
  ((ushort4*)xo)[(size_t)d * 64 + lane] = o4;
}

// ---------------- agg1 + fused node-attention MLP (ex precomputed) ----------------
__global__ __launch_bounds__(256) void agg1na_kernel(
    const u16* __restrict__ h, const float* __restrict__ exl,
    const int* __restrict__ rowp, const int* __restrict__ col,
    const float* __restrict__ bias, float* __restrict__ xo,
    const float* __restrict__ Wna1, const float* __restrict__ bna1,
    const float* __restrict__ Wna2, const float* __restrict__ bna2,
    float* __restrict__ na) {
  __shared__ float Ws[2048];
  __shared__ float W2s[32];
  __shared__ float xrow[4][64];
  for (int i = threadIdx.x; i < 2048; i += 256) Ws[i] = Wna1[i];
  if (threadIdx.x < 32) W2s[threadIdx.x] = Wna2[threadIdx.x];
  __syncthreads();
  int wid = threadIdx.x >> 6, lane = threadIdx.x & 63;
  int d = blockIdx.x * 4 + wid;
  int rp0 = rowp[d], deg = rowp[d + 1] - rp0;
  float acc = 0.f, den = 0.f;
  for (int base = 0; base < deg; base += 64) {
    int i = base + lane;
    bool valid = i < deg;
    int s = valid ? col[rp0 + i] : 0;
    float ex = valid ? exl[rp0 + i] : 0.f;
    den += ex;
    int cnt = min(64, deg - base);
    int k8 = cnt & ~7;
    for (int k = 0; k < k8; k += 8) {
      int sA[8];
      float qA[8], hv[8];
#pragma unroll
      for (int u = 0; u < 8; ++u) {
        sA[u] = __builtin_amdgcn_readlane(s, k + u);
        qA[u] = readlane_f(ex, k + u);
      }
#pragma unroll
      for (int u = 0; u < 8; ++u) hv[u] = b2f(h[(size_t)sA[u] * 64 + lane]);
      float p0 = qA[0] * hv[0] + qA[1] * hv[1];
      float p1 = qA[2] * hv[2] + qA[3] * hv[3];
      float p2 = qA[4] * hv[4] + qA[5] * hv[5];
      float p3 = qA[6] * hv[6] + qA[7] * hv[7];
      acc += (p0 + p1) + (p2 + p3);
    }
    for (int k = k8; k < cnt; ++k) {
      int sk = __builtin_amdgcn_readlane(s, k);
      float qk = readlane_f(ex, k);
      acc += qk * b2f(h[(size_t)sk * 64 + lane]);
    }
  }
#pragma unroll
  for (int o = 32; o; o >>= 1) den += __shfl_xor(den, o, 64);
  float v = acc / den + bias[lane];
  v = (v > 0.f) ? v : expm1f(v);
  xo[(size_t)d * 64 + lane] = v;
  // per-wave node-attention MLP on the in-LDS x3 row
  xrow[wid][lane] = v;
  __threadfence_block();
  int j = lane & 31;
  int coff = (lane >> 5) * 32;
  float hj = 0.f;
#pragma unroll
  for (int c = 0; c < 32; ++c) hj += xrow[wid][coff + c] * Ws[(coff + c) * 32 + j];
  hj += __shfl_xor(hj, 32, 64);
  hj += bna1[j];
  float r = fmaxf(hj, 0.f) * W2s[j];
#pragma unroll
  for (int o = 16; o; o >>= 1) r += __shfl_xor(r, o, 64);
  if (lane == 0) na[d] = __expf(r + bna2[0]);
}

// ---------------- na sum + write ----------------
__global__ void na_sum_kernel(const float* __restrict__ na, float* __restrict__ gsum) {
  __shared__ float s[4];
  float acc = 0.f;
  for (int i = blockIdx.x * blockDim.x + threadIdx.x; i < NN; i += gridDim.x * blockDim.x)
    acc += na[i];
  for (int o = 32; o; o >>= 1) acc += __shfl_xor(acc, o, 64);
  int wid = threadIdx.x >> 6, lane = threadIdx.x & 63;
  if (lane == 0) s[wid] = acc;
  __syncthreads();
  if (threadIdx.x == 0) atomicAdd(gsum, s[0] + s[1] + s[2] + s[3]);
}

__global__ void na_write_kernel(const float* __restrict__ na, const float* __restrict__ gsum,
                                float* __restrict__ out) {
  int n = blockIdx.x * blockDim.x + threadIdx.x;
  if (n >= NN) return;
  out[n] = na[n] / gsum[0];
}

// ---------------- pooling stage 1 ----------------
__global__ void pool1_kernel(const float* __restrict__ x3, const int* __restrict__ batch,
                             float* __restrict__ ppsum, float* __restrict__ ppmax) {
  int b = blockIdx.x, c = blockIdx.y;
  int lane = threadIdx.x & 63, wid = threadIdx.x >> 6;
  int lo = 0, hi = NN;
  while (lo < hi) { int m = (lo + hi) >> 1; if (batch[m] < b) lo = m + 1; else hi = m; }
  int start = lo;
  lo = start; hi = NN;
  while (lo < hi) { int m = (lo + hi) >> 1; if (batch[m] < b + 1) lo = m + 1; else hi = m; }
  int end = lo;
  int len = end - start;
  int c0 = start + (int)((long)len * c / PC);
  int c1 = start + (int)((long)len * (c + 1) / PC);
  float acc = 0.f, mx = -INFINITY;
  for (int n = c0 + wid; n < c1; n += 4) {
    float v = x3[(size_t)n * 64 + lane];
    acc += v;
    mx = fmaxf(mx, v);
  }
  __shared__ float ssum[4][64], smax[4][64];
  ssum[wid][lane] = acc;
  smax[wid][lane] = mx;
  __syncthreads();
  if (wid == 0) {
    acc = ssum[0][lane] + ssum[1][lane] + ssum[2][lane] + ssum[3][lane];
    mx = fmaxf(fmaxf(smax[0][lane], smax[1][lane]), fmaxf(smax[2][lane], smax[3][lane]));
    size_t o = ((size_t)c * BB + b) * 64 + lane;
    ppsum[o] = acc;
    ppmax[o] = mx;
  }
}

// ---------------- pooling fold + classifier ----------------
__global__ void pool2cls_kernel(const float* __restrict__ ppsum, const float* __restrict__ ppmax,
                                const int* __restrict__ batch, const float* __restrict__ Wc1,
                                const float* __restrict__ bc1, const float* __restrict__ Wc2,
                                const float* __restrict__ bc2, const float* __restrict__ Wc3,
                                const float* __restrict__ bc3, float* __restrict__ out) {
  __shared__ float g[128], h1[128], h2[64], scnt;
  int b = blockIdx.x, t = threadIdx.x;
  if (t == 0) {
    int lo = 0, hi = NN;
    while (lo < hi) { int m = (lo + hi) >> 1; if (batch[m] < b) lo = m + 1; else hi = m; }
    int start = lo;
    lo = start; hi = NN;
    while (lo < hi) { int m = (lo + hi) >> 1; if (batch[m] < b + 1) lo = m + 1; else hi = m; }
    scnt = (float)(lo - start);
  }
  float s = 0.f, m = -INFINITY;
  if (t < 64) {
#pragma unroll
    for (int c = 0; c < PC; ++c) {
      size_t o = ((size_t)c * BB + b) * 64 + t;
      s += ppsum[o];
      m = fmaxf(m, ppmax[o]);
    }
  }
  __syncthreads();
  float cnt = scnt;
  if (t < 64) {
    g[t] = (cnt > 0.f) ? s / fmaxf(cnt, 1.f) : 0.f;
    g[64 + t] = (cnt > 0.f) ? m : 0.f;
  }
  __syncthreads();
  float v = bc1[t];
  for (int k = 0; k < 128; ++k) v += g[k] * Wc1[k * 128 + t];
  h1[t] = fmaxf(v, 0.f);
  __syncthreads();
  if (t < 64) {
    float v2 = bc2[t];
    for (int k = 0; k < 128; ++k) v2 += h1[k] * Wc2[k * 64 + t];
    h2[t] = fmaxf(v2, 0.f);
  }
  __syncthreads();
  if (t == 0) {
    float z = bc3[0];
    for (int k = 0; k < 64; ++k) z += h2[k] * Wc3[k];
    out[b] = 1.f / (1.f + expf(-z));
  }
}

extern "C" void kernel_launch(void* const* d_in, const int* in_sizes, int n_in,
                              void* d_out, int out_size, void* d_ws, size_t ws_size,
                              hipStream_t stream) {
  const float* x    = (const float*)d_in[0];
  const int*   ei   = (const int*)d_in[1];
  const int*   batch= (const int*)d_in[2];
  const float* W1 = (const float*)d_in[3];
  const float* aS1= (const float*)d_in[4];
  const float* aD1= (const float*)d_in[5];
  const float* b1 = (const float*)d_in[6];
  const float* W2 = (const float*)d_in[7];
  const float* aS2= (const float*)d_in[8];
  const float* aD2= (const float*)d_in[9];
  const float* b2 = (const float*)d_in[10];
  const float* W3 = (const float*)d_in[11];
  const float* aS3= (const float*)d_in[12];
  const float* aD3= (const float*)d_in[13];
  const float* b3 = (const float*)d_in[14];
  const float* Wna1=(const float*)d_in[15];
  const float* bna1=(const float*)d_in[16];
  const float* Wna2=(const float*)d_in[17];
  const float* bna2=(const float*)d_in[18];
  const float* Wc1=(const float*)d_in[19];
  const float* bc1=(const float*)d_in[20];
  const float* Wc2=(const float*)d_in[21];
  const float* bc2=(const float*)d_in[22];
  const float* Wc3=(const float*)d_in[23];
  const float* bc3=(const float*)d_in[24];
  float* out = (float*)d_out;

  char* w = (char*)d_ws;
  size_t off = 0;
  auto alloc = [&](size_t bytes) {
    void* p = w + off;
    off = (off + bytes + 255) & ~(size_t)255;
    return p;
  };
  u16* xb   = (u16*)alloc((size_t)NP * 32 * 2);
  u16* bufA = (u16*)alloc((size_t)NP * 256 * 2);       // h3 (bf16)
  u16* bufB = (u16*)alloc((size_t)NP * 256 * 2);       // y1 / y2 / x3(fp32)
  u8*  h8   = (u8*)alloc((size_t)NP * 256);            // fp8 h1 / h2
  u16* W1t  = (u16*)alloc((size_t)256 * 32 * 2);
  u16* W2t  = (u16*)alloc((size_t)256 * 256 * 2);
  u16* W3t  = (u16*)alloc((size_t)64 * 256 * 2);
  float* asb  = (float*)alloc((size_t)NP * 4 * 4);
  float* adb  = (float*)alloc((size_t)NP * 4 * 4);
  float* nab  = (float*)alloc((size_t)NN * 4);
  float4* exl4 = (float4*)alloc((size_t)ETOT * 16);    // per-edge exp scores
  int* rowp = (int*)alloc((size_t)(NN + 1) * 4);
  int* cntb = (int*)alloc((size_t)NN * 4);
  int* curb = (int*)alloc((size_t)NN * 4);
  float* gsum = (float*)alloc(256);
  size_t zspan = (size_t)((char*)gsum + 256 - (char*)cntb);
  int* colb = (int*)alloc((size_t)ETOT * 4);
  int* part = (int*)alloc(128 * 4);
  float* ppsum = (float*)alloc((size_t)PC * BB * 64 * 4);
  float* ppmax = (float*)alloc((size_t)PC * BB * 64 * 4);
  float* x3 = (float*)bufB;
  float* exl1 = (float*)exl4;
  (void)ws_size; (void)in_sizes; (void)n_in; (void)out_size;

  hipMemsetAsync(cntb, 0, zspan, stream);

  count_kernel<<<(ETOT + 255) / 256, 256, 0, stream>>>(ei, cntb);
  scan1_kernel<<<98, 512, 0, stream>>>(cntb, rowp, part);
  scan2_kernel<<<1, 128, 0, stream>>>(part, rowp);
  scan3_kernel<<<98, 512, 0, stream>>>(rowp, part);
  fill_kernel<<<(ETOT + 255) / 256, 256, 0, stream>>>(ei, rowp, curb, colb);

  const int PREP_TOT = NP * 32 + 8192 + 65536 + 16384;
  prep_kernel<<<(PREP_TOT + 255) / 256, 256, 0, stream>>>(x, W1, W2, W3, xb, W1t, W2t, W3t);

  const int GX = NP / 128;  // 392
  // layer 1: 15(->32) -> 256 (fp8 h, 128x128 tile)
  gemm128_kernel<32><<<dim3(GX, 2), 256, 0, stream>>>(xb, W1t, h8, 32, aS1, aD1, asb, adb);
  escore4_kernel<1><<<12500, 256, 0, stream>>>(asb, adb, rowp, colb, exl4);
  agg4_kernel<1><<<12500, 256, 0, stream>>>(h8, exl4, rowp, colb, b1, bufB);
  // layer 2: 256 -> 256 (fp8 h, 128x128 tile)
  gemm128_kernel<64><<<dim3(GX, 2), 256, 0, stream>>>(bufB, W2t, h8, 256, aS2, aD2, asb, adb);
  escore4_kernel<2><<<12500, 256, 0, stream>>>(asb, adb, rowp, colb, exl4);
  agg4_kernel<2><<<12500, 256, 0, stream>>>(h8, exl4, rowp, colb, b2, bufB);
  // layer 3: 256 -> 64 (bf16 h) + fused node-attention MLP
  gemm64_kernel<<<GX, 256, 0, stream>>>(bufB, W3t, bufA, 256, aS3, aD3, asb, adb);
  escore1_kernel<<<12500, 256, 0, stream>>>(asb, adb, rowp, colb, exl1);
  agg1na_kernel<<<12500, 256, 0, stream>>>(bufA, exl1, rowp, colb, b3, x3,
                                           Wna1, bna1, Wna2, bna2, nab);

  na_sum_kernel<<<196, 256, 0, stream>>>(nab, gsum);
  na_write_kernel<<<(NN + 255) / 256, 256, 0, stream>>>(nab, gsum, out + BB);
  pool1_kernel<<<dim3(BB, PC), 256, 0, stream>>>(x3, batch, ppsum, ppmax);
  pool2cls_kernel<<<BB, 128, 0, stream>>>(ppsum, ppmax, batch, Wc1, bc1, Wc2, bc2,
                                          Wc3, bc3, out);
}

// Round 15
// 359.250 us; speedup vs baseline: 1.0699x; 1.0373x over previous
//
#include <hip/hip_runtime.h>
#include <math.h>

#define NN 50000
#define NP 50176   // NN padded to 392*128 for guard-free GEMM
#define EE 800000
#define ETOT (EE + NN)
#define BB 50
#define PC 16      // pooling chunks per graph
#define BWD 128    // dsts per fill bucket
#define NBUCK 391  // ceil(NN/BWD)
#define TILE 8192  // edges per binA block

typedef unsigned short u16;
typedef unsigned char u8;
typedef __attribute__((ext_vector_type(8))) short short8;
typedef __attribute__((ext_vector_type(8))) unsigned short ushort8;
typedef __attribute__((ext_vector_type(4))) float floatx4;
typedef __attribute__((ext_vector_type(2))) float floatx2;

__device__ __forceinline__ float b2f(u16 u) {
  return __int_as_float(((int)u) << 16);
}
__device__ __forceinline__ u16 f2b(float f) {
  unsigned u = __float_as_uint(f);
  unsigned r = (u + 0x7fffu + ((u >> 16) & 1u)) >> 16;
  return (u16)r;
}
__device__ __forceinline__ u8 f2f8(float v) {
  return (u8)(__builtin_amdgcn_cvt_pk_fp8_f32(v, v, 0, false) & 0xFF);
}
__device__ __forceinline__ float readlane_f(float v, int l) {
  return __int_as_float(__builtin_amdgcn_readlane(__float_as_int(v), l));
}

// ---------------- CSR build ----------------
__global__ void count_kernel(const int* __restrict__ ei, int* __restrict__ cnt) {
  int e = blockIdx.x * blockDim.x + threadIdx.x;
  if (e >= ETOT) return;
  int d = (e < EE) ? ei[EE + e] : (e - EE);
  atomicAdd(&cnt[d], 1);
}

__global__ void scan1_kernel(const int* __restrict__ cnt, int* __restrict__ rowp,
                             int* __restrict__ part) {
  __shared__ int s[512];
  int t = threadIdx.x;
  int i = blockIdx.x * 512 + t;
  int v = (i < NN) ? cnt[i] : 0;
  s[t] = v;
  __syncthreads();
  for (int off = 1; off < 512; off <<= 1) {
    int add = (t >= off) ? s[t - off] : 0;
    __syncthreads();
    s[t] += add;
    __syncthreads();
  }
  if (i < NN) rowp[i] = s[t] - v;
  if (t == 511) part[blockIdx.x] = s[511];
}

__global__ void scan2_kernel(int* __restrict__ part, int* __restrict__ rowp) {
  __shared__ int s[128];
  int t = threadIdx.x;
  int v = (t < 98) ? part[t] : 0;
  s[t] = v;
  __syncthreads();
  for (int off = 1; off < 128; off <<= 1) {
    int add = (t >= off) ? s[t - off] : 0;
    __syncthreads();
    s[t] += add;
    __syncthreads();
  }
  if (t < 98) part[t] = s[t] - v;
  if (t == 97) rowp[NN] = s[97];
}

__global__ void scan3_kernel(int* __restrict__ rowp, const int* __restrict__ part) {
  int i = blockIdx.x * 512 + threadIdx.x;
  if (i < NN) rowp[i] += part[blockIdx.x];
}

// bucket cursors start at the bucket's CSR base (free from rowp)
__global__ void curinit_kernel(const int* __restrict__ rowp, int* __restrict__ cur_b) {
  int t = threadIdx.x;
  if (t < NBUCK) cur_b[t] = rowp[t * BWD];
}

// binA: tile -> LDS histogram -> scan -> reserve -> stage bucket-ordered -> coalesced append
__global__ __launch_bounds__(256) void binA_kernel(const int* __restrict__ ei,
                                                   int* __restrict__ cur_b,
                                                   unsigned* __restrict__ pairs) {
  __shared__ unsigned staged[TILE];  // 32KB, pack = s | dl<<16 | b<<23
  __shared__ int hist[512];          // padded for scan
  __shared__ int hoff[512];
  __shared__ int gbase[NBUCK];
  __shared__ int hcur[NBUCK];
  __shared__ int wsum[4];
  int t = threadIdx.x;
  int lane = t & 63, wid = t >> 6;
  int e0 = blockIdx.x * TILE;
  int tc = min(TILE, ETOT - e0);
  for (int i = t; i < 512; i += 256) hist[i] = 0;
  __syncthreads();
  // pass 1: histogram
  for (int i = t; i < tc; i += 256) {
    int e = e0 + i;
    int d = (e < EE) ? ei[EE + e] : (e - EE);
    atomicAdd(&hist[d >> 7], 1);
  }
  __syncthreads();
  // scan 512 entries: thread t owns 2t, 2t+1
  int a = hist[2 * t], b = hist[2 * t + 1];
  int sv = a + b;
  int v = sv;
#pragma unroll
  for (int off = 1; off < 64; off <<= 1) {
    int u = __shfl_up(v, off, 64);
    if (lane >= off) v += u;
  }
  if (lane == 63) wsum[wid] = v;
  __syncthreads();
  int wpre = 0;
  for (int ww = 0; ww < wid; ++ww) wpre += wsum[ww];
  int excl = v + wpre - sv;
  hoff[2 * t] = excl;
  hoff[2 * t + 1] = excl + a;
  __syncthreads();
  // reserve global space per bucket; init staging cursors
  for (int i = t; i < NBUCK; i += 256) {
    int n = hist[i];
    gbase[i] = (n > 0) ? atomicAdd(&cur_b[i], n) : 0;
    hcur[i] = hoff[i];
  }
  __syncthreads();
  // pass 2: stage (bucket-ordered in LDS)
  for (int i = t; i < tc; i += 256) {
    int e = e0 + i;
    int s, d;
    if (e < EE) { s = ei[e]; d = ei[EE + e]; } else { s = e - EE; d = s; }
    int bk = d >> 7;
    int slot = atomicAdd(&hcur[bk], 1);
    staged[slot] = (unsigned)s | ((unsigned)(d & 127) << 16) | ((unsigned)bk << 23);
  }
  __syncthreads();
  // pass 3: near-coalesced append to global bucket regions
  for (int i = t; i < tc; i += 256) {
    unsigned pk = staged[i];
    int bk = pk >> 23;
    pairs[gbase[bk] + (i - hoff[bk])] = pk;
  }
}

// scatterB: one block per bucket; scatter within the bucket's small CSR slice
__global__ __launch_bounds__(256) void scatterB_kernel(const unsigned* __restrict__ pairs,
                                                       const int* __restrict__ rowp,
                                                       int* __restrict__ col) {
  __shared__ int lbase[BWD];
  __shared__ int lcur[BWD];
  int t = threadIdx.x;
  int d0 = blockIdx.x * BWD;
  if (t < BWD) {
    int d = d0 + t;
    lbase[t] = rowp[(d < NN) ? d : NN];
    lcur[t] = 0;
  }
  __syncthreads();
  int p0 = rowp[d0];
  int dend = d0 + BWD;
  int p1 = rowp[(dend < NN) ? dend : NN];
  for (int i = p0 + t; i < p1; i += 256) {
    unsigned pk = pairs[i];
    int s = pk & 0xFFFF;
    int dl = (pk >> 16) & 0x7F;
    int p = atomicAdd(&lcur[dl], 1);
    col[lbase[dl] + p] = s;
  }
}

// ---------------- fused dtype prep ----------------
__global__ void prep_kernel(const float* __restrict__ x, const float* __restrict__ W1,
                            const float* __restrict__ W2, const float* __restrict__ W3,
                            u16* __restrict__ xb, u16* __restrict__ W1t,
                            u16* __restrict__ W2t, u16* __restrict__ W3t) {
  const int T0 = NP * 32, T1 = T0 + 8192, T2 = T1 + 65536, T3 = T2 + 16384;
  int i = blockIdx.x * 256 + threadIdx.x;
  if (i < T0) {
    int n = i >> 5, c = i & 31;
    xb[i] = (n < NN && c < 15) ? f2b(x[n * 15 + c]) : (u16)0;
  } else if (i < T1) {
    int j = i - T0, n = j >> 5, k = j & 31;
    W1t[j] = (k < 15) ? f2b(W1[k * 256 + n]) : (u16)0;
  } else if (i < T2) {
    int j = i - T1, n = j >> 8, k = j & 255;
    W2t[j] = f2b(W2[k * 256 + n]);
  } else if (i < T3) {
    int j = i - T2, n = j >> 8, k = j & 255;
    W3t[j] = f2b(W3[k * 64 + n]);
  }
}

// ---------------- 128x128 bf16 MFMA GEMM -> fp8 h + fused scores (H=4) ----------------
template <int BK>
__global__ __launch_bounds__(256) void gemm128_kernel(
    const u16* __restrict__ A, const u16* __restrict__ Bt, u8* __restrict__ C8,
    int K, const float* __restrict__ aS, const float* __restrict__ aD,
    float* __restrict__ as_o, float* __restrict__ ad_o) {
  __shared__ u16 Al[128][BK + 8];
  __shared__ u16 Bl[128][BK + 8];
  int R0 = blockIdx.x * 128, C0 = blockIdx.y * 128;
  int wid = threadIdx.x >> 6, lane = threadIdx.x & 63;
  int wr = (wid >> 1) * 64, wc = (wid & 1) * 64;
  int lrow = lane & 15, lk8 = (lane >> 4) * 8;
  int rq = (lane >> 4) * 4;
  const int Q8 = BK / 8;
  const int nA8 = 128 * Q8;
  floatx4 acc[4][4];
#pragma unroll
  for (int i = 0; i < 4; ++i)
#pragma unroll
    for (int j = 0; j < 4; ++j) acc[i][j] = (floatx4){0.f, 0.f, 0.f, 0.f};

  for (int k0 = 0; k0 < K; k0 += BK) {
    for (int c = threadIdx.x; c < 2 * nA8; c += 256) {
      if (c < nA8) {
        int r = c / Q8, o = (c % Q8) * 8;
        *(ushort8*)&Al[r][o] = *(const ushort8*)&A[(size_t)(R0 + r) * K + k0 + o];
      } else {
        int c2 = c - nA8;
        int r = c2 / Q8, o = (c2 % Q8) * 8;
        *(ushort8*)&Bl[r][o] = *(const ushort8*)&Bt[(size_t)(C0 + r) * K + k0 + o];
      }
    }
    __syncthreads();
#pragma unroll
    for (int ks = 0; ks < BK / 32; ++ks) {
      short8 a[4], b[4];
#pragma unroll
      for (int i = 0; i < 4; ++i) a[i] = *(const short8*)&Al[wr + i * 16 + lrow][ks * 32 + lk8];
#pragma unroll
      for (int j = 0; j < 4; ++j) b[j] = *(const short8*)&Bl[wc + j * 16 + lrow][ks * 32 + lk8];
#pragma unroll
      for (int i = 0; i < 4; ++i)
#pragma unroll
        for (int j = 0; j < 4; ++j)
          acc[i][j] = __builtin_amdgcn_mfma_f32_16x16x32_bf16(a[i], b[j], acc[i][j], 0, 0, 0);
    }
    __syncthreads();
  }
#pragma unroll
  for (int i = 0; i < 4; ++i)
#pragma unroll
    for (int j = 0; j < 4; ++j)
#pragma unroll
      for (int q = 0; q < 4; ++q) {
        int gr = R0 + wr + i * 16 + rq + q;
        int gc = C0 + wc + j * 16 + lrow;
        C8[(size_t)gr * 256 + gc] = f2f8(acc[i][j][q]);
      }
  int hb = blockIdx.y * 2 + (wid & 1);
  float wS[4], wD[4];
#pragma unroll
  for (int j = 0; j < 4; ++j) {
    wS[j] = aS[hb * 64 + j * 16 + lrow];
    wD[j] = aD[hb * 64 + j * 16 + lrow];
  }
#pragma unroll
  for (int i = 0; i < 4; ++i)
#pragma unroll
    for (int q = 0; q < 4; ++q) {
      float vS = acc[i][0][q] * wS[0] + acc[i][1][q] * wS[1] +
                 acc[i][2][q] * wS[2] + acc[i][3][q] * wS[3];
      float vD = acc[i][0][q] * wD[0] + acc[i][1][q] * wD[1] +
                 acc[i][2][q] * wD[2] + acc[i][3][q] * wD[3];
#pragma unroll
      for (int o = 8; o; o >>= 1) {
        vS += __shfl_xor(vS, o, 64);
        vD += __shfl_xor(vD, o, 64);
      }
      if (lrow == 0) {
        int gr = R0 + wr + i * 16 + rq + q;
        as_o[(size_t)gr * 4 + hb] = vS;
        ad_o[(size_t)gr * 4 + hb] = vD;
      }
    }
}

// ---------------- 128x64 bf16 GEMM (layer 3) + scores (H=1) ----------------
__global__ __launch_bounds__(256) void gemm64_kernel(
    const u16* __restrict__ A, const u16* __restrict__ Bt, u16* __restrict__ C,
    int K, const float* __restrict__ aS, const float* __restrict__ aD,
    float* __restrict__ as_o, float* __restrict__ ad_o) {
  const int BK = 64;
  __shared__ u16 Al[128][BK + 8];
  __shared__ u16 Bl[64][BK + 8];
  __shared__ float sS[4][64], sD[4][64];
  int R0 = blockIdx.x * 128;
  int wid = threadIdx.x >> 6, lane = threadIdx.x & 63;
  int wr = (wid >> 1) * 64, wc = (wid & 1) * 32;
  int lrow = lane & 15, lk8 = (lane >> 4) * 8;
  int rq = (lane >> 4) * 4;
  const int Q4 = BK / 4;
  const int nA = 128 * Q4, nB = 64 * Q4;
  floatx4 acc[4][2];
#pragma unroll
  for (int i = 0; i < 4; ++i)
#pragma unroll
    for (int j = 0; j < 2; ++j) acc[i][j] = (floatx4){0.f, 0.f, 0.f, 0.f};

  for (int k0 = 0; k0 < K; k0 += BK) {
    for (int c = threadIdx.x; c < nA + nB; c += 256) {
      if (c < nA) {
        int r = c / Q4, o = (c % Q4) * 4;
        *(ushort4*)&Al[r][o] = *(const ushort4*)&A[(size_t)(R0 + r) * K + k0 + o];
      } else {
        int c2 = c - nA;
        int r = c2 / Q4, o = (c2 % Q4) * 4;
        *(ushort4*)&Bl[r][o] = *(const ushort4*)&Bt[(size_t)r * K + k0 + o];
      }
    }
    __syncthreads();
#pragma unroll
    for (int ks = 0; ks < BK / 32; ++ks) {
      short8 a[4], b[2];
#pragma unroll
      for (int i = 0; i < 4; ++i) a[i] = *(const short8*)&Al[wr + i * 16 + lrow][ks * 32 + lk8];
#pragma unroll
      for (int j = 0; j < 2; ++j) b[j] = *(const short8*)&Bl[wc + j * 16 + lrow][ks * 32 + lk8];
#pragma unroll
      for (int i = 0; i < 4; ++i)
#pragma unroll
        for (int j = 0; j < 2; ++j)
          acc[i][j] = __builtin_amdgcn_mfma_f32_16x16x32_bf16(a[i], b[j], acc[i][j], 0, 0, 0);
    }
    __syncthreads();
  }
#pragma unroll
  for (int i = 0; i < 4; ++i)
#pragma unroll
    for (int j = 0; j < 2; ++j)
#pragma unroll
      for (int q = 0; q < 4; ++q) {
        int gr = R0 + wr + i * 16 + rq + q;
        C[(size_t)gr * 64 + wc + j * 16 + lrow] = f2b(acc[i][j][q]);
      }
  float wS0 = aS[wc + lrow], wS1 = aS[wc + 16 + lrow];
  float wD0 = aD[wc + lrow], wD1 = aD[wc + 16 + lrow];
#pragma unroll
  for (int i = 0; i < 4; ++i)
#pragma unroll
    for (int q = 0; q < 4; ++q) {
      float vS = acc[i][0][q] * wS0 + acc[i][1][q] * wS1;
      float vD = acc[i][0][q] * wD0 + acc[i][1][q] * wD1;
#pragma unroll
      for (int o = 8; o; o >>= 1) {
        vS += __shfl_xor(vS, o, 64);
        vD += __shfl_xor(vD, o, 64);
      }
      if (lrow == 0) {
        int rl = i * 16 + rq + q;
        sS[wid][rl] = vS;
        sD[wid][rl] = vD;
      }
    }
  __syncthreads();
  if (threadIdx.x < 128) {
    int p = threadIdx.x >> 6, r = threadIdx.x & 63;
    int gr = R0 + p * 64 + r;
    as_o[gr] = sS[2 * p][r] + sS[2 * p + 1][r];
    ad_o[gr] = sD[2 * p][r] + sD[2 * p + 1][r];
  }
}

// ---------------- per-dst-wave score precompute ----------------
template <int LAYER>
__global__ __launch_bounds__(256) void escore4_kernel(
    const float* __restrict__ as_i, const float* __restrict__ ad_i,
    const int* __restrict__ rowp, const int* __restrict__ col,
    float4* __restrict__ exl) {
  int wid = threadIdx.x >> 6, lane = threadIdx.x & 63;
  int d = blockIdx.x * 4 + wid;
  int rp0 = rowp[d], rp1 = rowp[d + 1];
  float4 add = *(const float4*)&ad_i[(size_t)d * 4];
  for (int i = rp0 + lane; i < rp1; i += 64) {
    int s = col[i];
    float4 a = *(const float4*)&as_i[(size_t)s * 4];
    float e0 = a.x + add.x, e1 = a.y + add.y, e2 = a.z + add.z, e3 = a.w + add.w;
    e0 = (e0 > 0.f) ? e0 : 0.2f * e0;
    e1 = (e1 > 0.f) ? e1 : 0.2f * e1;
    e2 = (e2 > 0.f) ? e2 : 0.2f * e2;
    e3 = (e3 > 0.f) ? e3 : 0.2f * e3;
    exl[i] = make_float4(__expf(e0), __expf(e1), __expf(e2), __expf(e3));
  }
}

__global__ __launch_bounds__(256) void escore1_kernel(
    const float* __restrict__ as_i, const float* __restrict__ ad_i,
    const int* __restrict__ rowp, const int* __restrict__ col,
    float* __restrict__ exl) {
  int wid = threadIdx.x >> 6, lane = threadIdx.x & 63;
  int d = blockIdx.x * 4 + wid;
  int rp0 = rowp[d], rp1 = rowp[d + 1];
  float add = ad_i[d];
  for (int i = rp0 + lane; i < rp1; i += 64) {
    float e = as_i[col[i]] + add;
    e = (e > 0.f) ? e : 0.2f * e;
    exl[i] = __expf(e);
  }
}

// ---------------- agg4: batch-8 inner, ex from precomputed coalesced array ----------------
template <int LAYER>
__global__ __launch_bounds__(256) void agg4_kernel(
    const u8* __restrict__ h8, const float4* __restrict__ exl,
    const int* __restrict__ rowp, const int* __restrict__ col,
    const float* __restrict__ bias, u16* __restrict__ xo) {
  __shared__ float exs[4][64][4];
  int wid = threadIdx.x >> 6, lane = threadIdx.x & 63;
  int d = blockIdx.x * 4 + wid;
  int rp0 = rowp[d], deg = rowp[d + 1] - rp0;
  int hj = lane >> 4;
  int lq = lane << 2;
  float a0 = 0.f, a1 = 0.f, a2 = 0.f, a3 = 0.f;
  float den0 = 0.f, den1 = 0.f, den2 = 0.f, den3 = 0.f;

  for (int base = 0; base < deg; base += 64) {
    int i = base + lane;
    bool valid = i < deg;
    int s = valid ? col[rp0 + i] : 0;
    float4 xv = valid ? exl[rp0 + i] : make_float4(0.f, 0.f, 0.f, 0.f);
    den0 += xv.x; den1 += xv.y; den2 += xv.z; den3 += xv.w;
    *(float4*)&exs[wid][lane][0] = xv;
    __threadfence_block();
    int cnt = min(64, deg - base);
    int k8 = cnt & ~7;
    for (int k = 0; k < k8; k += 8) {
      unsigned wv[8];
      float qv[8];
#pragma unroll
      for (int u = 0; u < 8; ++u) {
        int sk = __builtin_amdgcn_readlane(s, k + u);
        qv[u] = exs[wid][k + u][hj];
        wv[u] = *(const unsigned*)&h8[(size_t)sk * 256 + lq];
      }
#pragma unroll
      for (int u = 0; u < 8; ++u) {
        floatx2 lo = __builtin_amdgcn_cvt_pk_f32_fp8(wv[u], false);
        floatx2 hi = __builtin_amdgcn_cvt_pk_f32_fp8(wv[u], true);
        a0 += qv[u] * lo.x;
        a1 += qv[u] * lo.y;
        a2 += qv[u] * hi.x;
        a3 += qv[u] * hi.y;
      }
    }
    for (int k = k8; k < cnt; ++k) {
      int sk = __builtin_amdgcn_readlane(s, k);
      float qk = exs[wid][k][hj];
      unsigned wv = *(const unsigned*)&h8[(size_t)sk * 256 + lq];
      floatx2 lo = __builtin_amdgcn_cvt_pk_f32_fp8(wv, false);
      floatx2 hi = __builtin_amdgcn_cvt_pk_f32_fp8(wv, true);
      a0 += qk * lo.x;
      a1 += qk * lo.y;
      a2 += qk * hi.x;
      a3 += qk * hi.y;
    }
  }
#pragma unroll
  for (int o = 32; o; o >>= 1) {
    den0 += __shfl_xor(den0, o, 64);
    den1 += __shfl_xor(den1, o, 64);
    den2 += __shfl_xor(den2, o, 64);
    den3 += __shfl_xor(den3, o, 64);
  }
  float den = (hj == 0) ? den0 : (hj == 1) ? den1 : (hj == 2) ? den2 : den3;
  float inv = 1.f / den;
  float4 bv = *(const float4*)&bias[lq];
  float v0 = a0 * inv + bv.x;
  float v1 = a1 * inv + bv.y;
  float v2 = a2 * inv + bv.z;
  float v3 = a3 * inv + bv.w;
  v0 = (v0 > 0.f) ? v0 : expm1f(v0);
  v1 = (v1 > 0.f) ? v1 : expm1f(v1);
  v2 = (v2 > 0.f) ? v2 : expm1f(v2);
  v3 = (v3 > 0.f) ? v3 : expm1f(v3);
  ushort4 o4;
  o4.x = f2b(v0); o4.y = f2b(v1); o4.z = f2b(v2); o4.w = f2b(v3);
  ((ushort4*)xo)[(size_t)d * 64 + lane] = o4;
}

// ---------------- agg1 + fused node-attention MLP (ex precomputed) ----------------
__global__ __launch_bounds__(256) void agg1na_kernel(
    const u16* __restrict__ h, const float* __restrict__ exl,
    const int* __restrict__ rowp, const int* __restrict__ col,
    const float* __restrict__ bias, float* __restrict__ xo,
    const float* __restrict__ Wna1, const float* __restrict__ bna1,
    const float* __restrict__ Wna2, const float* __restrict__ bna2,
    float* __restrict__ na) {
  __shared__ float Ws[2048];
  __shared__ float W2s[32];
  __shared__ float xrow[4][64];
  for (int i = threadIdx.x; i < 2048; i += 256) Ws[i] = Wna1[i];
  if (threadIdx.x < 32) W2s[threadIdx.x] = Wna2[threadIdx.x];
  __syncthreads();
  int wid = threadIdx.x >> 6, lane = threadIdx.x & 63;
  int d = blockIdx.x * 4 + wid;
  int rp0 = rowp[d], deg = rowp[d + 1] - rp0;
  float acc = 0.f, den = 0.f;
  for (int base = 0; base < deg; base += 64) {
    int i = base + lane;
    bool valid = i < deg;
    int s = valid ? col[rp0 + i] : 0;
    float ex = valid ? exl[rp0 + i] : 0.f;
    den += ex;
    int cnt = min(64, deg - base);
    int k8 = cnt & ~7;
    for (int k = 0; k < k8; k += 8) {
      int sA[8];
      float qA[8], hv[8];
#pragma unroll
      for (int u = 0; u < 8; ++u) {
        sA[u] = __builtin_amdgcn_readlane(s, k + u);
        qA[u] = readlane_f(ex, k + u);
      }
#pragma unroll
      for (int u = 0; u < 8; ++u) hv[u] = b2f(h[(size_t)sA[u] * 64 + lane]);
      float p0 = qA[0] * hv[0] + qA[1] * hv[1];
      float p1 = qA[2] * hv[2] + qA[3] * hv[3];
      float p2 = qA[4] * hv[4] + qA[5] * hv[5];
      float p3 = qA[6] * hv[6] + qA[7] * hv[7];
      acc += (p0 + p1) + (p2 + p3);
    }
    for (int k = k8; k < cnt; ++k) {
      int sk = __builtin_amdgcn_readlane(s, k);
      float qk = readlane_f(ex, k);
      acc += qk * b2f(h[(size_t)sk * 64 + lane]);
    }
  }
#pragma unroll
  for (int o = 32; o; o >>= 1) den += __shfl_xor(den, o, 64);
  float v = acc / den + bias[lane];
  v = (v > 0.f) ? v : expm1f(v);
  xo[(size_t)d * 64 + lane] = v;
  xrow[wid][lane] = v;
  __threadfence_block();
  int j = lane & 31;
  int coff = (lane >> 5) * 32;
  float hj = 0.f;
#pragma unroll
  for (int c = 0; c < 32; ++c) hj += xrow[wid][coff + c] * Ws[(coff + c) * 32 + j];
  hj += __shfl_xor(hj, 32, 64);
  hj += bna1[j];
  float r = fmaxf(hj, 0.f) * W2s[j];
#pragma unroll
  for (int o = 16; o; o >>= 1) r += __shfl_xor(r, o, 64);
  if (lane == 0) na[d] = __expf(r + bna2[0]);
}

// ---------------- na sum + write ----------------
__global__ void na_sum_kernel(const float* __restrict__ na, float* __restrict__ gsum) {
  __shared__ float s[4];
  float acc = 0.f;
  for (int i = blockIdx.x * blockDim.x + threadIdx.x; i < NN; i += gridDim.x * blockDim.x)
    acc += na[i];
  for (int o = 32; o; o >>= 1) acc += __shfl_xor(acc, o, 64);
  int wid = threadIdx.x >> 6, lane = threadIdx.x & 63;
  if (lane == 0) s[wid] = acc;
  __syncthreads();
  if (threadIdx.x == 0) atomicAdd(gsum, s[0] + s[1] + s[2] + s[3]);
}

__global__ void na_write_kernel(const float* __restrict__ na, const float* __restrict__ gsum,
                                float* __restrict__ out) {
  int n = blockIdx.x * blockDim.x + threadIdx.x;
  if (n >= NN) return;
  out[n] = na[n] / gsum[0];
}

// ---------------- pooling stage 1 ----------------
__global__ void pool1_kernel(const float* __restrict__ x3, const int* __restrict__ batch,
                             float* __restrict__ ppsum, float* __restrict__ ppmax) {
  int b = blockIdx.x, c = blockIdx.y;
  int lane = threadIdx.x & 63, wid = threadIdx.x >> 6;
  int lo = 0, hi = NN;
  while (lo < hi) { int m = (lo + hi) >> 1; if (batch[m] < b) lo = m + 1; else hi = m; }
  int start = lo;
  lo = start; hi = NN;
  while (lo < hi) { int m = (lo + hi) >> 1; if (batch[m] < b + 1) lo = m + 1; else hi = m; }
  int end = lo;
  int len = end - start;
  int c0 = start + (int)((long)len * c / PC);
  int c1 = start + (int)((long)len * (c + 1) / PC);
  float acc = 0.f, mx = -INFINITY;
  for (int n = c0 + wid; n < c1; n += 4) {
    float v = x3[(size_t)n * 64 + lane];
    acc += v;
    mx = fmaxf(mx, v);
  }
  __shared__ float ssum[4][64], smax[4][64];
  ssum[wid][lane] = acc;
  smax[wid][lane] = mx;
  __syncthreads();
  if (wid == 0) {
    acc = ssum[0][lane] + ssum[1][lane] + ssum[2][lane] + ssum[3][lane];
    mx = fmaxf(fmaxf(smax[0][lane], smax[1][lane]), fmaxf(smax[2][lane], smax[3][lane]));
    size_t o = ((size_t)c * BB + b) * 64 + lane;
    ppsum[o] = acc;
    ppmax[o] = mx;
  }
}

// ---------------- pooling fold + classifier ----------------
__global__ void pool2cls_kernel(const float* __restrict__ ppsum, const float* __restrict__ ppmax,
                                const int* __restrict__ batch, const float* __restrict__ Wc1,
                                const float* __restrict__ bc1, const float* __restrict__ Wc2,
                                const float* __restrict__ bc2, const float* __restrict__ Wc3,
                                const float* __restrict__ bc3, float* __restrict__ out) {
  __shared__ float g[128], h1[128], h2[64], scnt;
  int b = blockIdx.x, t = threadIdx.x;
  if (t == 0) {
    int lo = 0, hi = NN;
    while (lo < hi) { int m = (lo + hi) >> 1; if (batch[m] < b) lo = m + 1; else hi = m; }
    int start = lo;
    lo = start; hi = NN;
    while (lo < hi) { int m = (lo + hi) >> 1; if (batch[m] < b + 1) lo = m + 1; else hi = m; }
    scnt = (float)(lo - start);
  }
  float s = 0.f, m = -INFINITY;
  if (t < 64) {
#pragma unroll
    for (int c = 0; c < PC; ++c) {
      size_t o = ((size_t)c * BB + b) * 64 + t;
      s += ppsum[o];
      m = fmaxf(m, ppmax[o]);
    }
  }
  __syncthreads();
  float cnt = scnt;
  if (t < 64) {
    g[t] = (cnt > 0.f) ? s / fmaxf(cnt, 1.f) : 0.f;
    g[64 + t] = (cnt > 0.f) ? m : 0.f;
  }
  __syncthreads();
  float v = bc1[t];
  for (int k = 0; k < 128; ++k) v += g[k] * Wc1[k * 128 + t];
  h1[t] = fmaxf(v, 0.f);
  __syncthreads();
  if (t < 64) {
    float v2 = bc2[t];
    for (int k = 0; k < 128; ++k) v2 += h1[k] * Wc2[k * 64 + t];
    h2[t] = fmaxf(v2, 0.f);
  }
  __syncthreads();
  if (t == 0) {
    float z = bc3[0];
    for (int k = 0; k < 64; ++k) z += h2[k] * Wc3[k];
    out[b] = 1.f / (1.f + expf(-z));
  }
}

extern "C" void kernel_launch(void* const* d_in, const int* in_sizes, int n_in,
                              void* d_out, int out_size, void* d_ws, size_t ws_size,
                              hipStream_t stream) {
  const float* x    = (const float*)d_in[0];
  const int*   ei   = (const int*)d_in[1];
  const int*   batch= (const int*)d_in[2];
  const float* W1 = (const float*)d_in[3];
  const float* aS1= (const float*)d_in[4];
  const float* aD1= (const float*)d_in[5];
  const float* b1 = (const float*)d_in[6];
  const float* W2 = (const float*)d_in[7];
  const float* aS2= (const float*)d_in[8];
  const float* aD2= (const float*)d_in[9];
  const float* b2 = (const float*)d_in[10];
  const float* W3 = (const float*)d_in[11];
  const float* aS3= (const float*)d_in[12];
  const float* aD3= (const float*)d_in[13];
  const float* b3 = (const float*)d_in[14];
  const float* Wna1=(const float*)d_in[15];
  const float* bna1=(const float*)d_in[16];
  const float* Wna2=(const float*)d_in[17];
  const float* bna2=(const float*)d_in[18];
  const float* Wc1=(const float*)d_in[19];
  const float* bc1=(const float*)d_in[20];
  const float* Wc2=(const float*)d_in[21];
  const float* bc2=(const float*)d_in[22];
  const float* Wc3=(const float*)d_in[23];
  const float* bc3=(const float*)d_in[24];
  float* out = (float*)d_out;

  char* w = (char*)d_ws;
  size_t off = 0;
  auto alloc = [&](size_t bytes) {
    void* p = w + off;
    off = (off + bytes + 255) & ~(size_t)255;
    return p;
  };
  u16* xb   = (u16*)alloc((size_t)NP * 32 * 2);
  u16* bufA = (u16*)alloc((size_t)NP * 256 * 2);       // h3 (bf16)
  u16* bufB = (u16*)alloc((size_t)NP * 256 * 2);       // y1 / y2 / x3(fp32)
  u8*  h8   = (u8*)alloc((size_t)NP * 256);            // fp8 h1 / h2
  u16* W1t  = (u16*)alloc((size_t)256 * 32 * 2);
  u16* W2t  = (u16*)alloc((size_t)256 * 256 * 2);
  u16* W3t  = (u16*)alloc((size_t)64 * 256 * 2);
  float* asb  = (float*)alloc((size_t)NP * 4 * 4);
  float* adb  = (float*)alloc((size_t)NP * 4 * 4);
  float* nab  = (float*)alloc((size_t)NN * 4);
  float4* exl4 = (float4*)alloc((size_t)ETOT * 16);    // per-edge exp scores
  unsigned* pairs = (unsigned*)alloc((size_t)ETOT * 4);
  int* rowp = (int*)alloc((size_t)(NN + 1) * 4);
  int* cur_b = (int*)alloc((size_t)(NBUCK + 1) * 4);
  int* cntb = (int*)alloc((size_t)NN * 4);
  float* gsum = (float*)alloc(256);
  size_t zspan = (size_t)((char*)gsum + 256 - (char*)cntb);
  int* colb = (int*)alloc((size_t)ETOT * 4);
  int* part = (int*)alloc(128 * 4);
  float* ppsum = (float*)alloc((size_t)PC * BB * 64 * 4);
  float* ppmax = (float*)alloc((size_t)PC * BB * 64 * 4);
  float* x3 = (float*)bufB;
  float* exl1 = (float*)exl4;
  (void)ws_size; (void)in_sizes; (void)n_in; (void)out_size;

  hipMemsetAsync(cntb, 0, zspan, stream);

  count_kernel<<<(ETOT + 255) / 256, 256, 0, stream>>>(ei, cntb);
  scan1_kernel<<<98, 512, 0, stream>>>(cntb, rowp, part);
  scan2_kernel<<<1, 128, 0, stream>>>(part, rowp);
  scan3_kernel<<<98, 512, 0, stream>>>(rowp, part);
  curinit_kernel<<<1, 512, 0, stream>>>(rowp, cur_b);
  binA_kernel<<<(ETOT + TILE - 1) / TILE, 256, 0, stream>>>(ei, cur_b, pairs);
  scatterB_kernel<<<NBUCK, 256, 0, stream>>>(pairs, rowp, colb);

  const int PREP_TOT = NP * 32 + 8192 + 65536 + 16384;
  prep_kernel<<<(PREP_TOT + 255) / 256, 256, 0, stream>>>(x, W1, W2, W3, xb, W1t, W2t, W3t);

  const int GX = NP / 128;  // 392
  // layer 1: 15(->32) -> 256 (fp8 h, 128x128 tile)
  gemm128_kernel<32><<<dim3(GX, 2), 256, 0, stream>>>(xb, W1t, h8, 32, aS1, aD1, asb, adb);
  escore4_kernel<1><<<12500, 256, 0, stream>>>(asb, adb, rowp, colb, exl4);
  agg4_kernel<1><<<12500, 256, 0, stream>>>(h8, exl4, rowp, colb, b1, bufB);
  // layer 2: 256 -> 256 (fp8 h, 128x128 tile)
  gemm128_kernel<64><<<dim3(GX, 2), 256, 0, stream>>>(bufB, W2t, h8, 256, aS2, aD2, asb, adb);
  escore4_kernel<2><<<12500, 256, 0, stream>>>(asb, adb, rowp, colb, exl4);
  agg4_kernel<2><<<12500, 256, 0, stream>>>(h8, exl4, rowp, colb, b2, bufB);
  // layer 3: 256 -> 64 (bf16 h) + fused node-attention MLP
  gemm64_kernel<<<GX, 256, 0, stream>>>(bufB, W3t, bufA, 256, aS3, aD3, asb, adb);
  escore1_kernel<<<12500, 256, 0, stream>>>(asb, adb, rowp, colb, exl1);
  agg1na_kernel<<<12500, 256, 0, stream>>>(bufA, exl1, rowp, colb, b3, x3,
                                           Wna1, bna1, Wna2, bna2, nab);

  na_sum_kernel<<<196, 256, 0, stream>>>(nab, gsum);
  na_write_kernel<<<(NN + 255) / 256, 256, 0, stream>>>(nab, gsum, out + BB);
  pool1_kernel<<<dim3(BB, PC), 256, 0, stream>>>(x3, batch, ppsum, ppmax);
  pool2cls_kernel<<<BB, 128, 0, stream>>>(ppsum, ppmax, batch, Wc1, bc1, Wc2, bc2,
                                          Wc3, bc3, out);
}

// Round 16
// 356.244 us; speedup vs baseline: 1.0789x; 1.0084x over previous
//
#include <hip/hip_runtime.h>
#include <math.h>

#define NN 50000
#define NP 50176   // NN padded to 392*128 for guard-free GEMM
#define EE 800000
#define ETOT (EE + NN)
#define BB 50
#define PC 16      // pooling chunks per graph
#define BWD 128    // dsts per fill bucket
#define NBUCK 391  // ceil(NN/BWD)
#define TILE 8192  // edges per binA block

typedef unsigned short u16;
typedef unsigned char u8;
typedef __attribute__((ext_vector_type(8))) short short8;
typedef __attribute__((ext_vector_type(8))) unsigned short ushort8;
typedef __attribute__((ext_vector_type(4))) float floatx4;
typedef __attribute__((ext_vector_type(2))) float floatx2;
typedef __attribute__((ext_vector_type(4))) _Float16 half4;

__device__ __forceinline__ float b2f(u16 u) {
  return __int_as_float(((int)u) << 16);
}
__device__ __forceinline__ u16 f2b(float f) {
  unsigned u = __float_as_uint(f);
  unsigned r = (u + 0x7fffu + ((u >> 16) & 1u)) >> 16;
  return (u16)r;
}
__device__ __forceinline__ u8 f2f8(float v) {
  return (u8)(__builtin_amdgcn_cvt_pk_fp8_f32(v, v, 0, false) & 0xFF);
}
__device__ __forceinline__ float f8tof(unsigned b) {
  floatx2 lo = __builtin_amdgcn_cvt_pk_f32_fp8(b, false);
  return lo.x;
}
__device__ __forceinline__ float readlane_f(float v, int l) {
  return __int_as_float(__builtin_amdgcn_readlane(__float_as_int(v), l));
}

// ---------------- CSR build ----------------
__global__ void count_kernel(const int* __restrict__ ei, int* __restrict__ cnt) {
  int e = blockIdx.x * blockDim.x + threadIdx.x;
  if (e >= ETOT) return;
  int d = (e < EE) ? ei[EE + e] : (e - EE);
  atomicAdd(&cnt[d], 1);
}

__global__ void scan1_kernel(const int* __restrict__ cnt, int* __restrict__ rowp,
                             int* __restrict__ part) {
  __shared__ int s[512];
  int t = threadIdx.x;
  int i = blockIdx.x * 512 + t;
  int v = (i < NN) ? cnt[i] : 0;
  s[t] = v;
  __syncthreads();
  for (int off = 1; off < 512; off <<= 1) {
    int add = (t >= off) ? s[t - off] : 0;
    __syncthreads();
    s[t] += add;
    __syncthreads();
  }
  if (i < NN) rowp[i] = s[t] - v;
  if (t == 511) part[blockIdx.x] = s[511];
}

__global__ void scan2_kernel(int* __restrict__ part, int* __restrict__ rowp) {
  __shared__ int s[128];
  int t = threadIdx.x;
  int v = (t < 98) ? part[t] : 0;
  s[t] = v;
  __syncthreads();
  for (int off = 1; off < 128; off <<= 1) {
    int add = (t >= off) ? s[t - off] : 0;
    __syncthreads();
    s[t] += add;
    __syncthreads();
  }
  if (t < 98) part[t] = s[t] - v;
  if (t == 97) rowp[NN] = s[97];
}

__global__ void scan3_kernel(int* __restrict__ rowp, const int* __restrict__ part) {
  int i = blockIdx.x * 512 + threadIdx.x;
  if (i < NN) rowp[i] += part[blockIdx.x];
}

__global__ void curinit_kernel(const int* __restrict__ rowp, int* __restrict__ cur_b) {
  int t = threadIdx.x;
  if (t < NBUCK) cur_b[t] = rowp[t * BWD];
}

// binA: tile -> LDS histogram -> scan -> reserve -> stage bucket-ordered -> coalesced append
__global__ __launch_bounds__(256) void binA_kernel(const int* __restrict__ ei,
                                                   int* __restrict__ cur_b,
                                                   unsigned* __restrict__ pairs) {
  __shared__ unsigned staged[TILE];
  __shared__ int hist[512];
  __shared__ int hoff[512];
  __shared__ int gbase[NBUCK];
  __shared__ int hcur[NBUCK];
  __shared__ int wsum[4];
  int t = threadIdx.x;
  int lane = t & 63, wid = t >> 6;
  int e0 = blockIdx.x * TILE;
  int tc = min(TILE, ETOT - e0);
  for (int i = t; i < 512; i += 256) hist[i] = 0;
  __syncthreads();
  for (int i = t; i < tc; i += 256) {
    int e = e0 + i;
    int d = (e < EE) ? ei[EE + e] : (e - EE);
    atomicAdd(&hist[d >> 7], 1);
  }
  __syncthreads();
  int a = hist[2 * t], b = hist[2 * t + 1];
  int sv = a + b;
  int v = sv;
#pragma unroll
  for (int off = 1; off < 64; off <<= 1) {
    int u = __shfl_up(v, off, 64);
    if (lane >= off) v += u;
  }
  if (lane == 63) wsum[wid] = v;
  __syncthreads();
  int wpre = 0;
  for (int ww = 0; ww < wid; ++ww) wpre += wsum[ww];
  int excl = v + wpre - sv;
  hoff[2 * t] = excl;
  hoff[2 * t + 1] = excl + a;
  __syncthreads();
  for (int i = t; i < NBUCK; i += 256) {
    int n = hist[i];
    gbase[i] = (n > 0) ? atomicAdd(&cur_b[i], n) : 0;
    hcur[i] = hoff[i];
  }
  __syncthreads();
  for (int i = t; i < tc; i += 256) {
    int e = e0 + i;
    int s, d;
    if (e < EE) { s = ei[e]; d = ei[EE + e]; } else { s = e - EE; d = s; }
    int bk = d >> 7;
    int slot = atomicAdd(&hcur[bk], 1);
    staged[slot] = (unsigned)s | ((unsigned)(d & 127) << 16) | ((unsigned)bk << 23);
  }
  __syncthreads();
  for (int i = t; i < tc; i += 256) {
    unsigned pk = staged[i];
    int bk = pk >> 23;
    pairs[gbase[bk] + (i - hoff[bk])] = pk;
  }
}

__global__ __launch_bounds__(256) void scatterB_kernel(const unsigned* __restrict__ pairs,
                                                       const int* __restrict__ rowp,
                                                       int* __restrict__ col) {
  __shared__ int lbase[BWD];
  __shared__ int lcur[BWD];
  int t = threadIdx.x;
  int d0 = blockIdx.x * BWD;
  if (t < BWD) {
    int d = d0 + t;
    lbase[t] = rowp[(d < NN) ? d : NN];
    lcur[t] = 0;
  }
  __syncthreads();
  int p0 = rowp[d0];
  int dend = d0 + BWD;
  int p1 = rowp[(dend < NN) ? dend : NN];
  for (int i = p0 + t; i < p1; i += 256) {
    unsigned pk = pairs[i];
    int s = pk & 0xFFFF;
    int dl = (pk >> 16) & 0x7F;
    int p = atomicAdd(&lcur[dl], 1);
    col[lbase[dl] + p] = s;
  }
}

// ---------------- fused dtype prep ----------------
__global__ void prep_kernel(const float* __restrict__ x, const float* __restrict__ W1,
                            const float* __restrict__ W2, const float* __restrict__ W3,
                            u16* __restrict__ xb, u16* __restrict__ W1t,
                            u16* __restrict__ W2t, u16* __restrict__ W3t) {
  const int T0 = NP * 32, T1 = T0 + 8192, T2 = T1 + 65536, T3 = T2 + 16384;
  int i = blockIdx.x * 256 + threadIdx.x;
  if (i < T0) {
    int n = i >> 5, c = i & 31;
    xb[i] = (n < NN && c < 15) ? f2b(x[n * 15 + c]) : (u16)0;
  } else if (i < T1) {
    int j = i - T0, n = j >> 5, k = j & 31;
    W1t[j] = (k < 15) ? f2b(W1[k * 256 + n]) : (u16)0;
  } else if (i < T2) {
    int j = i - T1, n = j >> 8, k = j & 255;
    W2t[j] = f2b(W2[k * 256 + n]);
  } else if (i < T3) {
    int j = i - T2, n = j >> 8, k = j & 255;
    W3t[j] = f2b(W3[k * 64 + n]);
  }
}

// ---------------- 128x128 bf16 MFMA GEMM -> fp8 h + fused scores (H=4) ----------------
template <int BK>
__global__ __launch_bounds__(256) void gemm128_kernel(
    const u16* __restrict__ A, const u16* __restrict__ Bt, u8* __restrict__ C8,
    int K, const float* __restrict__ aS, const float* __restrict__ aD,
    float* __restrict__ as_o, float* __restrict__ ad_o) {
  __shared__ u16 Al[128][BK + 8];
  __shared__ u16 Bl[128][BK + 8];
  int R0 = blockIdx.x * 128, C0 = blockIdx.y * 128;
  int wid = threadIdx.x >> 6, lane = threadIdx.x & 63;
  int wr = (wid >> 1) * 64, wc = (wid & 1) * 64;
  int lrow = lane & 15, lk8 = (lane >> 4) * 8;
  int rq = (lane >> 4) * 4;
  const int Q8 = BK / 8;
  const int nA8 = 128 * Q8;
  floatx4 acc[4][4];
#pragma unroll
  for (int i = 0; i < 4; ++i)
#pragma unroll
    for (int j = 0; j < 4; ++j) acc[i][j] = (floatx4){0.f, 0.f, 0.f, 0.f};

  for (int k0 = 0; k0 < K; k0 += BK) {
    for (int c = threadIdx.x; c < 2 * nA8; c += 256) {
      if (c < nA8) {
        int r = c / Q8, o = (c % Q8) * 8;
        *(ushort8*)&Al[r][o] = *(const ushort8*)&A[(size_t)(R0 + r) * K + k0 + o];
      } else {
        int c2 = c - nA8;
        int r = c2 / Q8, o = (c2 % Q8) * 8;
        *(ushort8*)&Bl[r][o] = *(const ushort8*)&Bt[(size_t)(C0 + r) * K + k0 + o];
      }
    }
    __syncthreads();
#pragma unroll
    for (int ks = 0; ks < BK / 32; ++ks) {
      short8 a[4], b[4];
#pragma unroll
      for (int i = 0; i < 4; ++i) a[i] = *(const short8*)&Al[wr + i * 16 + lrow][ks * 32 + lk8];
#pragma unroll
      for (int j = 0; j < 4; ++j) b[j] = *(const short8*)&Bl[wc + j * 16 + lrow][ks * 32 + lk8];
#pragma unroll
      for (int i = 0; i < 4; ++i)
#pragma unroll
        for (int j = 0; j < 4; ++j)
          acc[i][j] = __builtin_amdgcn_mfma_f32_16x16x32_bf16(a[i], b[j], acc[i][j], 0, 0, 0);
    }
    __syncthreads();
  }
#pragma unroll
  for (int i = 0; i < 4; ++i)
#pragma unroll
    for (int j = 0; j < 4; ++j)
#pragma unroll
      for (int q = 0; q < 4; ++q) {
        int gr = R0 + wr + i * 16 + rq + q;
        int gc = C0 + wc + j * 16 + lrow;
        C8[(size_t)gr * 256 + gc] = f2f8(acc[i][j][q]);
      }
  int hb = blockIdx.y * 2 + (wid & 1);
  float wS[4], wD[4];
#pragma unroll
  for (int j = 0; j < 4; ++j) {
    wS[j] = aS[hb * 64 + j * 16 + lrow];
    wD[j] = aD[hb * 64 + j * 16 + lrow];
  }
#pragma unroll
  for (int i = 0; i < 4; ++i)
#pragma unroll
    for (int q = 0; q < 4; ++q) {
      float vS = acc[i][0][q] * wS[0] + acc[i][1][q] * wS[1] +
                 acc[i][2][q] * wS[2] + acc[i][3][q] * wS[3];
      float vD = acc[i][0][q] * wD[0] + acc[i][1][q] * wD[1] +
                 acc[i][2][q] * wD[2] + acc[i][3][q] * wD[3];
#pragma unroll
      for (int o = 8; o; o >>= 1) {
        vS += __shfl_xor(vS, o, 64);
        vD += __shfl_xor(vD, o, 64);
      }
      if (lrow == 0) {
        int gr = R0 + wr + i * 16 + rq + q;
        as_o[(size_t)gr * 4 + hb] = vS;
        ad_o[(size_t)gr * 4 + hb] = vD;
      }
    }
}

// ---------------- 128x64 bf16 GEMM (layer 3) -> fp8 h3 + scores (H=1) ----------------
__global__ __launch_bounds__(256) void gemm64_kernel(
    const u16* __restrict__ A, const u16* __restrict__ Bt, u8* __restrict__ C8,
    int K, const float* __restrict__ aS, const float* __restrict__ aD,
    float* __restrict__ as_o, float* __restrict__ ad_o) {
  const int BK = 64;
  __shared__ u16 Al[128][BK + 8];
  __shared__ u16 Bl[64][BK + 8];
  __shared__ float sS[4][64], sD[4][64];
  int R0 = blockIdx.x * 128;
  int wid = threadIdx.x >> 6, lane = threadIdx.x & 63;
  int wr = (wid >> 1) * 64, wc = (wid & 1) * 32;
  int lrow = lane & 15, lk8 = (lane >> 4) * 8;
  int rq = (lane >> 4) * 4;
  const int Q4 = BK / 4;
  const int nA = 128 * Q4, nB = 64 * Q4;
  floatx4 acc[4][2];
#pragma unroll
  for (int i = 0; i < 4; ++i)
#pragma unroll
    for (int j = 0; j < 2; ++j) acc[i][j] = (floatx4){0.f, 0.f, 0.f, 0.f};

  for (int k0 = 0; k0 < K; k0 += BK) {
    for (int c = threadIdx.x; c < nA + nB; c += 256) {
      if (c < nA) {
        int r = c / Q4, o = (c % Q4) * 4;
        *(ushort4*)&Al[r][o] = *(const ushort4*)&A[(size_t)(R0 + r) * K + k0 + o];
      } else {
        int c2 = c - nA;
        int r = c2 / Q4, o = (c2 % Q4) * 4;
        *(ushort4*)&Bl[r][o] = *(const ushort4*)&Bt[(size_t)r * K + k0 + o];
      }
    }
    __syncthreads();
#pragma unroll
    for (int ks = 0; ks < BK / 32; ++ks) {
      short8 a[4], b[2];
#pragma unroll
      for (int i = 0; i < 4; ++i) a[i] = *(const short8*)&Al[wr + i * 16 + lrow][ks * 32 + lk8];
#pragma unroll
      for (int j = 0; j < 2; ++j) b[j] = *(const short8*)&Bl[wc + j * 16 + lrow][ks * 32 + lk8];
#pragma unroll
      for (int i = 0; i < 4; ++i)
#pragma unroll
        for (int j = 0; j < 2; ++j)
          acc[i][j] = __builtin_amdgcn_mfma_f32_16x16x32_bf16(a[i], b[j], acc[i][j], 0, 0, 0);
    }
    __syncthreads();
  }
#pragma unroll
  for (int i = 0; i < 4; ++i)
#pragma unroll
    for (int j = 0; j < 2; ++j)
#pragma unroll
      for (int q = 0; q < 4; ++q) {
        int gr = R0 + wr + i * 16 + rq + q;
        C8[(size_t)gr * 64 + wc + j * 16 + lrow] = f2f8(acc[i][j][q]);
      }
  float wS0 = aS[wc + lrow], wS1 = aS[wc + 16 + lrow];
  float wD0 = aD[wc + lrow], wD1 = aD[wc + 16 + lrow];
#pragma unroll
  for (int i = 0; i < 4; ++i)
#pragma unroll
    for (int q = 0; q < 4; ++q) {
      float vS = acc[i][0][q] * wS0 + acc[i][1][q] * wS1;
      float vD = acc[i][0][q] * wD0 + acc[i][1][q] * wD1;
#pragma unroll
      for (int o = 8; o; o >>= 1) {
        vS += __shfl_xor(vS, o, 64);
        vD += __shfl_xor(vD, o, 64);
      }
      if (lrow == 0) {
        int rl = i * 16 + rq + q;
        sS[wid][rl] = vS;
        sD[wid][rl] = vD;
      }
    }
  __syncthreads();
  if (threadIdx.x < 128) {
    int p = threadIdx.x >> 6, r = threadIdx.x & 63;
    int gr = R0 + p * 64 + r;
    as_o[gr] = sS[2 * p][r] + sS[2 * p + 1][r];
    ad_o[gr] = sD[2 * p][r] + sD[2 * p + 1][r];
  }
}

// ---------------- per-dst-wave score precompute (fp16 out for H=4) ----------------
template <int LAYER>
__global__ __launch_bounds__(256) void escore4_kernel(
    const float* __restrict__ as_i, const float* __restrict__ ad_i,
    const int* __restrict__ rowp, const int* __restrict__ col,
    half4* __restrict__ exl) {
  int wid = threadIdx.x >> 6, lane = threadIdx.x & 63;
  int d = blockIdx.x * 4 + wid;
  int rp0 = rowp[d], rp1 = rowp[d + 1];
  float4 add = *(const float4*)&ad_i[(size_t)d * 4];
  for (int i = rp0 + lane; i < rp1; i += 64) {
    int s = col[i];
    float4 a = *(const float4*)&as_i[(size_t)s * 4];
    float e0 = a.x + add.x, e1 = a.y + add.y, e2 = a.z + add.z, e3 = a.w + add.w;
    e0 = (e0 > 0.f) ? e0 : 0.2f * e0;
    e1 = (e1 > 0.f) ? e1 : 0.2f * e1;
    e2 = (e2 > 0.f) ? e2 : 0.2f * e2;
    e3 = (e3 > 0.f) ? e3 : 0.2f * e3;
    half4 hv;
    hv.x = (_Float16)__expf(e0);
    hv.y = (_Float16)__expf(e1);
    hv.z = (_Float16)__expf(e2);
    hv.w = (_Float16)__expf(e3);
    exl[i] = hv;
  }
}

__global__ __launch_bounds__(256) void escore1_kernel(
    const float* __restrict__ as_i, const float* __restrict__ ad_i,
    const int* __restrict__ rowp, const int* __restrict__ col,
    float* __restrict__ exl) {
  int wid = threadIdx.x >> 6, lane = threadIdx.x & 63;
  int d = blockIdx.x * 4 + wid;
  int rp0 = rowp[d], rp1 = rowp[d + 1];
  float add = ad_i[d];
  for (int i = rp0 + lane; i < rp1; i += 64) {
    float e = as_i[col[i]] + add;
    e = (e > 0.f) ? e : 0.2f * e;
    exl[i] = __expf(e);
  }
}

// ---------------- agg4: batch-8 inner, fp16 exl, fp8 h ----------------
template <int LAYER>
__global__ __launch_bounds__(256) void agg4_kernel(
    const u8* __restrict__ h8, const half4* __restrict__ exl,
    const int* __restrict__ rowp, const int* __restrict__ col,
    const float* __restrict__ bias, u16* __restrict__ xo) {
  __shared__ float exs[4][64][4];
  int wid = threadIdx.x >> 6, lane = threadIdx.x & 63;
  int d = blockIdx.x * 4 + wid;
  int rp0 = rowp[d], deg = rowp[d + 1] - rp0;
  int hj = lane >> 4;
  int lq = lane << 2;
  float a0 = 0.f, a1 = 0.f, a2 = 0.f, a3 = 0.f;
  float den0 = 0.f, den1 = 0.f, den2 = 0.f, den3 = 0.f;

  for (int base = 0; base < deg; base += 64) {
    int i = base + lane;
    bool valid = i < deg;
    int s = valid ? col[rp0 + i] : 0;
    float x0 = 0.f, x1 = 0.f, x2 = 0.f, x3 = 0.f;
    if (valid) {
      half4 xh = exl[rp0 + i];
      x0 = (float)xh.x; x1 = (float)xh.y; x2 = (float)xh.z; x3 = (float)xh.w;
    }
    den0 += x0; den1 += x1; den2 += x2; den3 += x3;
    *(float4*)&exs[wid][lane][0] = make_float4(x0, x1, x2, x3);
    __threadfence_block();
    int cnt = min(64, deg - base);
    int k8 = cnt & ~7;
    for (int k = 0; k < k8; k += 8) {
      unsigned wv[8];
      float qv[8];
#pragma unroll
      for (int u = 0; u < 8; ++u) {
        int sk = __builtin_amdgcn_readlane(s, k + u);
        qv[u] = exs[wid][k + u][hj];
        wv[u] = *(const unsigned*)&h8[(size_t)sk * 256 + lq];
      }
#pragma unroll
      for (int u = 0; u < 8; ++u) {
        floatx2 lo = __builtin_amdgcn_cvt_pk_f32_fp8(wv[u], false);
        floatx2 hi = __builtin_amdgcn_cvt_pk_f32_fp8(wv[u], true);
        a0 += qv[u] * lo.x;
        a1 += qv[u] * lo.y;
        a2 += qv[u] * hi.x;
        a3 += qv[u] * hi.y;
      }
    }
    for (int k = k8; k < cnt; ++k) {
      int sk = __builtin_amdgcn_readlane(s, k);
      float qk = exs[wid][k][hj];
      unsigned wv = *(const unsigned*)&h8[(size_t)sk * 256 + lq];
      floatx2 lo = __builtin_amdgcn_cvt_pk_f32_fp8(wv, false);
      floatx2 hi = __builtin_amdgcn_cvt_pk_f32_fp8(wv, true);
      a0 += qk * lo.x;
      a1 += qk * lo.y;
      a2 += qk * hi.x;
      a3 += qk * hi.y;
    }
  }
#pragma unroll
  for (int o = 32; o; o >>= 1) {
    den0 += __shfl_xor(den0, o, 64);
    den1 += __shfl_xor(den1, o, 64);
    den2 += __shfl_xor(den2, o, 64);
    den3 += __shfl_xor(den3, o, 64);
  }
  float den = (hj == 0) ? den0 : (hj == 1) ? den1 : (hj == 2) ? den2 : den3;
  float inv = 1.f / den;
  float4 bv = *(const float4*)&bias[lq];
  float v0 = a0 * inv + bv.x;
  float v1 = a1 * inv + bv.y;
  float v2 = a2 * inv + bv.z;
  float v3 = a3 * inv + bv.w;
  v0 = (v0 > 0.f) ? v0 : expm1f(v0);
  v1 = (v1 > 0.f) ? v1 : expm1f(v1);
  v2 = (v2 > 0.f) ? v2 : expm1f(v2);
  v3 = (v3 > 0.f) ? v3 : expm1f(v3);
  ushort4 o4;
  o4.x = f2b(v0); o4.y = f2b(v1); o4.z = f2b(v2); o4.w = f2b(v3);
  ((ushort4*)xo)[(size_t)d * 64 + lane] = o4;
}

// ---------------- agg1 (fp8 h3) + fused node-attention MLP ----------------
__global__ __launch_bounds__(256) void agg1na_kernel(
    const u8* __restrict__ h8, const float* __restrict__ exl,
    const int* __restrict__ rowp, const int* __restrict__ col,
    const float* __restrict__ bias, float* __restrict__ xo,
    const float* __restrict__ Wna1, const float* __restrict__ bna1,
    const float* __restrict__ Wna2, const float* __restrict__ bna2,
    float* __restrict__ na) {
  __shared__ float Ws[2048];
  __shared__ float W2s[32];
  __shared__ float xrow[4][64];
  for (int i = threadIdx.x; i < 2048; i += 256) Ws[i] = Wna1[i];
  if (threadIdx.x < 32) W2s[threadIdx.x] = Wna2[threadIdx.x];
  __syncthreads();
  int wid = threadIdx.x >> 6, lane = threadIdx.x & 63;
  int d = blockIdx.x * 4 + wid;
  int rp0 = rowp[d], deg = rowp[d + 1] - rp0;
  float acc = 0.f, den = 0.f;
  for (int base = 0; base < deg; base += 64) {
    int i = base + lane;
    bool valid = i < deg;
    int s = valid ? col[rp0 + i] : 0;
    float ex = valid ? exl[rp0 + i] : 0.f;
    den += ex;
    int cnt = min(64, deg - base);
    int k8 = cnt & ~7;
    for (int k = 0; k < k8; k += 8) {
      int sA[8];
      float qA[8];
      unsigned wv[8];
#pragma unroll
      for (int u = 0; u < 8; ++u) {
        sA[u] = __builtin_amdgcn_readlane(s, k + u);
        qA[u] = readlane_f(ex, k + u);
      }
#pragma unroll
      for (int u = 0; u < 8; ++u) wv[u] = h8[(size_t)sA[u] * 64 + lane];
      float p0 = qA[0] * f8tof(wv[0]) + qA[1] * f8tof(wv[1]);
      float p1 = qA[2] * f8tof(wv[2]) + qA[3] * f8tof(wv[3]);
      float p2 = qA[4] * f8tof(wv[4]) + qA[5] * f8tof(wv[5]);
      float p3 = qA[6] * f8tof(wv[6]) + qA[7] * f8tof(wv[7]);
      acc += (p0 + p1) + (p2 + p3);
    }
    for (int k = k8; k < cnt; ++k) {
      int sk = __builtin_amdgcn_readlane(s, k);
      float qk = readlane_f(ex, k);
      acc += qk * f8tof((unsigned)h8[(size_t)sk * 64 + lane]);
    }
  }
#pragma unroll
  for (int o = 32; o; o >>= 1) den += __shfl_xor(den, o, 64);
  float v = acc / den + bias[lane];
  v = (v > 0.f) ? v : expm1f(v);
  xo[(size_t)d * 64 + lane] = v;
  xrow[wid][lane] = v;
  __threadfence_block();
  int j = lane & 31;
  int coff = (lane >> 5) * 32;
  float hj = 0.f;
#pragma unroll
  for (int c = 0; c < 32; ++c) hj += xrow[wid][coff + c] * Ws[(coff + c) * 32 + j];
  hj += __shfl_xor(hj, 32, 64);
  hj += bna1[j];
  float r = fmaxf(hj, 0.f) * W2s[j];
#pragma unroll
  for (int o = 16; o; o >>= 1) r += __shfl_xor(r, o, 64);
  if (lane == 0) na[d] = __expf(r + bna2[0]);
}

// ---------------- na sum + write ----------------
__global__ void na_sum_kernel(const float* __restrict__ na, float* __restrict__ gsum) {
  __shared__ float s[4];
  float acc = 0.f;
  for (int i = blockIdx.x * blockDim.x + threadIdx.x; i < NN; i += gridDim.x * blockDim.x)
    acc += na[i];
  for (int o = 32; o; o >>= 1) acc += __shfl_xor(acc, o, 64);
  int wid = threadIdx.x >> 6, lane = threadIdx.x & 63;
  if (lane == 0) s[wid] = acc;
  __syncthreads();
  if (threadIdx.x == 0) atomicAdd(gsum, s[0] + s[1] + s[2] + s[3]);
}

__global__ void na_write_kernel(const float* __restrict__ na, const float* __restrict__ gsum,
                                float* __restrict__ out) {
  int n = blockIdx.x * blockDim.x + threadIdx.x;
  if (n >= NN) return;
  out[n] = na[n] / gsum[0];
}

// ---------------- pooling stage 1 ----------------
__global__ void pool1_kernel(const float* __restrict__ x3, const int* __restrict__ batch,
                             float* __restrict__ ppsum, float* __restrict__ ppmax) {
  int b = blockIdx.x, c = blockIdx.y;
  int lane = threadIdx.x & 63, wid = threadIdx.x >> 6;
  int lo = 0, hi = NN;
  while (lo < hi) { int m = (lo + hi) >> 1; if (batch[m] < b) lo = m + 1; else hi = m; }
  int start = lo;
  lo = start; hi = NN;
  while (lo < hi) { int m = (lo + hi) >> 1; if (batch[m] < b + 1) lo = m + 1; else hi = m; }
  int end = lo;
  int len = end - start;
  int c0 = start + (int)((long)len * c / PC);
  int c1 = start + (int)((long)len * (c + 1) / PC);
  float acc = 0.f, mx = -INFINITY;
  for (int n = c0 + wid; n < c1; n += 4) {
    float v = x3[(size_t)n * 64 + lane];
    acc += v;
    mx = fmaxf(mx, v);
  }
  __shared__ float ssum[4][64], smax[4][64];
  ssum[wid][lane] = acc;
  smax[wid][lane] = mx;
  __syncthreads();
  if (wid == 0) {
    acc = ssum[0][lane] + ssum[1][lane] + ssum[2][lane] + ssum[3][lane];
    mx = fmaxf(fmaxf(smax[0][lane], smax[1][lane]), fmaxf(smax[2][lane], smax[3][lane]));
    size_t o = ((size_t)c * BB + b) * 64 + lane;
    ppsum[o] = acc;
    ppmax[o] = mx;
  }
}

// ---------------- pooling fold + classifier ----------------
__global__ void pool2cls_kernel(const float* __restrict__ ppsum, const float* __restrict__ ppmax,
                                const int* __restrict__ batch, const float* __restrict__ Wc1,
                                const float* __restrict__ bc1, const float* __restrict__ Wc2,
                                const float* __restrict__ bc2, const float* __restrict__ Wc3,
                                const float* __restrict__ bc3, float* __restrict__ out) {
  __shared__ float g[128], h1[128], h2[64], scnt;
  int b = blockIdx.x, t = threadIdx.x;
  if (t == 0) {
    int lo = 0, hi = NN;
    while (lo < hi) { int m = (lo + hi) >> 1; if (batch[m] < b) lo = m + 1; else hi = m; }
    int start = lo;
    lo = start; hi = NN;
    while (lo < hi) { int m = (lo + hi) >> 1; if (batch[m] < b + 1) lo = m + 1; else hi = m; }
    scnt = (float)(lo - start);
  }
  float s = 0.f, m = -INFINITY;
  if (t < 64) {
#pragma unroll
    for (int c = 0; c < PC; ++c) {
      size_t o = ((size_t)c * BB + b) * 64 + t;
      s += ppsum[o];
      m = fmaxf(m, ppmax[o]);
    }
  }
  __syncthreads();
  float cnt = scnt;
  if (t < 64) {
    g[t] = (cnt > 0.f) ? s / fmaxf(cnt, 1.f) : 0.f;
    g[64 + t] = (cnt > 0.f) ? m : 0.f;
  }
  __syncthreads();
  float v = bc1[t];
  for (int k = 0; k < 128; ++k) v += g[k] * Wc1[k * 128 + t];
  h1[t] = fmaxf(v, 0.f);
  __syncthreads();
  if (t < 64) {
    float v2 = bc2[t];
    for (int k = 0; k < 128; ++k) v2 += h1[k] * Wc2[k * 64 + t];
    h2[t] = fmaxf(v2, 0.f);
  }
  __syncthreads();
  if (t == 0) {
    float z = bc3[0];
    for (int k = 0; k < 64; ++k) z += h2[k] * Wc3[k];
    out[b] = 1.f / (1.f + expf(-z));
  }
}

extern "C" void kernel_launch(void* const* d_in, const int* in_sizes, int n_in,
                              void* d_out, int out_size, void* d_ws, size_t ws_size,
                              hipStream_t stream) {
  const float* x    = (const float*)d_in[0];
  const int*   ei   = (const int*)d_in[1];
  const int*   batch= (const int*)d_in[2];
  const float* W1 = (const float*)d_in[3];
  const float* aS1= (const float*)d_in[4];
  const float* aD1= (const float*)d_in[5];
  const float* b1 = (const float*)d_in[6];
  const float* W2 = (const float*)d_in[7];
  const float* aS2= (const float*)d_in[8];
  const float* aD2= (const float*)d_in[9];
  const float* b2 = (const float*)d_in[10];
  const float* W3 = (const float*)d_in[11];
  const float* aS3= (const float*)d_in[12];
  const float* aD3= (const float*)d_in[13];
  const float* b3 = (const float*)d_in[14];
  const float* Wna1=(const float*)d_in[15];
  const float* bna1=(const float*)d_in[16];
  const float* Wna2=(const float*)d_in[17];
  const float* bna2=(const float*)d_in[18];
  const float* Wc1=(const float*)d_in[19];
  const float* bc1=(const float*)d_in[20];
  const float* Wc2=(const float*)d_in[21];
  const float* bc2=(const float*)d_in[22];
  const float* Wc3=(const float*)d_in[23];
  const float* bc3=(const float*)d_in[24];
  float* out = (float*)d_out;

  char* w = (char*)d_ws;
  size_t off = 0;
  auto alloc = [&](size_t bytes) {
    void* p = w + off;
    off = (off + bytes + 255) & ~(size_t)255;
    return p;
  };
  u16* xb   = (u16*)alloc((size_t)NP * 32 * 2);
  u8*  h83  = (u8*)alloc((size_t)NP * 64);             // fp8 h3 (L2-resident: 3.2MB)
  u16* bufB = (u16*)alloc((size_t)NP * 256 * 2);       // y1 / y2 / x3(fp32)
  u8*  h8   = (u8*)alloc((size_t)NP * 256);            // fp8 h1 / h2
  u16* W1t  = (u16*)alloc((size_t)256 * 32 * 2);
  u16* W2t  = (u16*)alloc((size_t)256 * 256 * 2);
  u16* W3t  = (u16*)alloc((size_t)64 * 256 * 2);
  float* asb  = (float*)alloc((size_t)NP * 4 * 4);
  float* adb  = (float*)alloc((size_t)NP * 4 * 4);
  float* nab  = (float*)alloc((size_t)NN * 4);
  half4* exl4 = (half4*)alloc((size_t)ETOT * 8);       // per-edge fp16 exp scores
  unsigned* pairs = (unsigned*)alloc((size_t)ETOT * 4);
  int* rowp = (int*)alloc((size_t)(NN + 1) * 4);
  int* cur_b = (int*)alloc((size_t)(NBUCK + 1) * 4);
  int* cntb = (int*)alloc((size_t)NN * 4);
  float* gsum = (float*)alloc(256);
  size_t zspan = (size_t)((char*)gsum + 256 - (char*)cntb);
  int* colb = (int*)alloc((size_t)ETOT * 4);
  int* part = (int*)alloc(128 * 4);
  float* ppsum = (float*)alloc((size_t)PC * BB * 64 * 4);
  float* ppmax = (float*)alloc((size_t)PC * BB * 64 * 4);
  float* x3 = (float*)bufB;
  float* exl1 = (float*)exl4;
  (void)ws_size; (void)in_sizes; (void)n_in; (void)out_size;

  hipMemsetAsync(cntb, 0, zspan, stream);

  count_kernel<<<(ETOT + 255) / 256, 256, 0, stream>>>(ei, cntb);
  scan1_kernel<<<98, 512, 0, stream>>>(cntb, rowp, part);
  scan2_kernel<<<1, 128, 0, stream>>>(part, rowp);
  scan3_kernel<<<98, 512, 0, stream>>>(rowp, part);
  curinit_kernel<<<1, 512, 0, stream>>>(rowp, cur_b);
  binA_kernel<<<(ETOT + TILE - 1) / TILE, 256, 0, stream>>>(ei, cur_b, pairs);
  scatterB_kernel<<<NBUCK, 256, 0, stream>>>(pairs, rowp, colb);

  const int PREP_TOT = NP * 32 + 8192 + 65536 + 16384;
  prep_kernel<<<(PREP_TOT + 255) / 256, 256, 0, stream>>>(x, W1, W2, W3, xb, W1t, W2t, W3t);

  const int GX = NP / 128;  // 392
  // layer 1: 15(->32) -> 256 (fp8 h, 128x128 tile)
  gemm128_kernel<32><<<dim3(GX, 2), 256, 0, stream>>>(xb, W1t, h8, 32, aS1, aD1, asb, adb);
  escore4_kernel<1><<<12500, 256, 0, stream>>>(asb, adb, rowp, colb, exl4);
  agg4_kernel<1><<<12500, 256, 0, stream>>>(h8, exl4, rowp, colb, b1, bufB);
  // layer 2: 256 -> 256 (fp8 h, 128x128 tile)
  gemm128_kernel<64><<<dim3(GX, 2), 256, 0, stream>>>(bufB, W2t, h8, 256, aS2, aD2, asb, adb);
  escore4_kernel<2><<<12500, 256, 0, stream>>>(asb, adb, rowp, colb, exl4);
  agg4_kernel<2><<<12500, 256, 0, stream>>>(h8, exl4, rowp, colb, b2, bufB);
  // layer 3: 256 -> 64 (fp8 h3) + fused node-attention MLP
  gemm64_kernel<<<GX, 256, 0, stream>>>(bufB, W3t, h83, 256, aS3, aD3, asb, adb);
  escore1_kernel<<<12500, 256, 0, stream>>>(asb, adb, rowp, colb, exl1);
  agg1na_kernel<<<12500, 256, 0, stream>>>(h83, exl1, rowp, colb, b3, x3,
                                           Wna1, bna1, Wna2, bna2, nab);

  na_sum_kernel<<<196, 256, 0, stream>>>(nab, gsum);
  na_write_kernel<<<(NN + 255) / 256, 256, 0, stream>>>(nab, gsum, out + BB);
  pool1_kernel<<<dim3(BB, PC), 256, 0, stream>>>(x3, batch, ppsum, ppmax);
  pool2cls_kernel<<<BB, 128, 0, stream>>>(ppsum, ppmax, batch, Wc1, bc1, Wc2, bc2,
                                          Wc3, bc3, out);
}